// Round 1
// baseline (20280.992 us; speedup 1.0000x reference)
//
#include <hip/hip_runtime.h>
#include <math.h>

#define TT 2048
#define NB 8

// ---------- Phase 0: Cinv = (H^T R^-1 H)^-1 (32x32), HtRinv (32x64) ----------
__global__ __launch_bounds__(256) void k_setup(const float* __restrict__ Hw,
                                               const float* __restrict__ logR,
                                               float* __restrict__ cinv,
                                               float* __restrict__ htr) {
  __shared__ float C[32][33];
  __shared__ float rinv[64];
  int tid = threadIdx.x;
  if (tid < 64) rinv[tid] = expf(-logR[tid]);
  __syncthreads();
  int i = tid >> 3, j0 = (tid & 7) << 2;
  float a0 = 0.f, a1 = 0.f, a2 = 0.f, a3 = 0.f;
  for (int o = 0; o < 64; ++o) {
    float hio = Hw[o * 32 + i] * rinv[o];
    a0 += hio * Hw[o * 32 + j0];
    a1 += hio * Hw[o * 32 + j0 + 1];
    a2 += hio * Hw[o * 32 + j0 + 2];
    a3 += hio * Hw[o * 32 + j0 + 3];
  }
  C[i][j0] = a0; C[i][j0 + 1] = a1; C[i][j0 + 2] = a2; C[i][j0 + 3] = a3;
  for (int e = 0; e < 8; ++e) {
    int idx = tid * 8 + e;
    int ii = idx >> 6, o = idx & 63;
    htr[idx] = Hw[o * 32 + ii] * rinv[o];
  }
  __syncthreads();
  // in-place Jordan-exchange inversion of C (SPD, no pivoting)
  for (int k = 0; k < 32; ++k) {
    float ip = 1.0f / C[k][k];
    __syncthreads();
    if (tid < 32 && tid != k) C[k][tid] = -C[k][tid] * ip;
    __syncthreads();
    if (i != k) {
      float f = C[i][k];
      for (int q = 0; q < 4; ++q) {
        int j = j0 + q;
        if (j != k) C[i][j] += f * C[k][j];
      }
    }
    __syncthreads();
    if (tid < 32) {
      if (tid == k) C[k][k] = ip; else C[tid][k] *= ip;
    }
    __syncthreads();
  }
  cinv[i * 32 + j0]     = C[i][j0];
  cinv[i * 32 + j0 + 1] = C[i][j0 + 1];
  cinv[i * 32 + j0 + 2] = C[i][j0 + 2];
  cinv[i * 32 + j0 + 3] = C[i][j0 + 3];
}

// ---------- Phase 1: probs (B,T) and z = emb @ obs_w^T + obs_b ----------
__global__ __launch_bounds__(256) void k_obs(const float* __restrict__ emb,
                                             const float* __restrict__ w1,
                                             const float* __restrict__ b1,
                                             const float* __restrict__ w2,
                                             const float* __restrict__ b2,
                                             const float* __restrict__ ow,
                                             const float* __restrict__ ob,
                                             float* __restrict__ probs_out,
                                             float* __restrict__ zws) {
  int wave = threadIdx.x >> 6, lane = threadIdx.x & 63;
  int row = blockIdx.x * 4 + wave;  // 0..16383
  float xv = emb[(size_t)row * 64 + lane];
  // h = relu(x @ W1^T + b1), lane computes h[lane]
  const float4* w1v = (const float4*)(w1 + lane * 64);
  float hacc = b1[lane];
#pragma unroll
  for (int i4 = 0; i4 < 16; ++i4) {
    float4 wv = w1v[i4];
    hacc += __shfl(xv, i4 * 4, 64) * wv.x + __shfl(xv, i4 * 4 + 1, 64) * wv.y +
            __shfl(xv, i4 * 4 + 2, 64) * wv.z + __shfl(xv, i4 * 4 + 3, 64) * wv.w;
  }
  float h = fmaxf(hacc, 0.f);
  float s = h * w2[lane];
#pragma unroll
  for (int off = 32; off; off >>= 1) s += __shfl_xor(s, off, 64);
  float prob = 1.0f / (1.0f + expf(-(s + b2[0])));
  if (lane == 0) probs_out[row] = prob;
  // z = x @ obs_w^T + obs_b
  const float4* owv = (const float4*)(ow + lane * 64);
  float zacc = ob[lane];
#pragma unroll
  for (int i4 = 0; i4 < 16; ++i4) {
    float4 wv = owv[i4];
    zacc += __shfl(xv, i4 * 4, 64) * wv.x + __shfl(xv, i4 * 4 + 1, 64) * wv.y +
            __shfl(xv, i4 * 4 + 2, 64) * wv.z + __shfl(xv, i4 * 4 + 3, 64) * wv.w;
  }
  zws[(size_t)row * 64 + lane] = zacc;
}

// ---------- Phase 1b: gate[t] = any_b(probs[b][t] > 0.5) ----------
__global__ void k_gate(const float* __restrict__ probs_out, int* __restrict__ gate) {
  int t = blockIdx.x * 256 + threadIdx.x;
  if (t < TT) {
    int g = 0;
    for (int b = 0; b < NB; ++b) g |= (probs_out[b * TT + t] > 0.5f) ? 1 : 0;
    gate[t] = g;
  }
}

// ---------- Phase 2: the Riccati scan (one workgroup per batch) ----------
__global__ __launch_bounds__(256) void k_scan(const float* __restrict__ Fg,
                                              const float* __restrict__ logQ,
                                              const float* __restrict__ probs_out,
                                              const int* __restrict__ gate,
                                              const float* __restrict__ cinv,
                                              float* __restrict__ covs,
                                              float* __restrict__ su_ws) {
  __shared__ float fL[32][36], ftL[32][36], ciL[32][36];
  __shared__ float sigL[32][36], t1L[32][36], pL[32][36], wL[32][36];
  __shared__ float qdL[32];
  __shared__ float probL[TT];
  __shared__ int gateL[TT];
  const int b = blockIdx.x, tid = threadIdx.x;
  for (int idx = tid; idx < 1024; idx += 256) {
    int i = idx >> 5, j = idx & 31;
    float fv = Fg[idx];
    fL[i][j] = fv;
    ftL[j][i] = fv;
    ciL[i][j] = cinv[idx];
    sigL[i][j] = (i == j) ? 0.01f : 0.f;
  }
  if (tid < 32) qdL[tid] = expf(logQ[tid]);
  for (int idx = tid; idx < TT; idx += 256) {
    probL[idx] = probs_out[b * TT + idx];
    gateL[idx] = gate[idx];
  }
  __syncthreads();
  const int r = tid >> 3, c0 = (tid & 7) << 2;
  const int lane = tid & 63;
  const int rr = lane & 31, hh = lane >> 5;

#pragma unroll 1
  for (int t = 0; t < TT; ++t) {
    const float a3 = probL[t];
    const int g = gateL[t];
    // R1: t1 = F @ Sigma
    float4 acc = {0.f, 0.f, 0.f, 0.f};
#pragma unroll
    for (int k = 0; k < 32; ++k) {
      float lv = fL[r][k];
      float4 rv = *(const float4*)&sigL[k][c0];
      acc.x = fmaf(lv, rv.x, acc.x); acc.y = fmaf(lv, rv.y, acc.y);
      acc.z = fmaf(lv, rv.z, acc.z); acc.w = fmaf(lv, rv.w, acc.w);
    }
    *(float4*)&t1L[r][c0] = acc;
    __syncthreads();
    // R2: P = t1 @ F^T + diag(Qd)
    acc.x = acc.y = acc.z = acc.w = 0.f;
#pragma unroll
    for (int k = 0; k < 32; ++k) {
      float lv = t1L[r][k];
      float4 rv = *(const float4*)&ftL[k][c0];
      acc.x = fmaf(lv, rv.x, acc.x); acc.y = fmaf(lv, rv.y, acc.y);
      acc.z = fmaf(lv, rv.z, acc.z); acc.w = fmaf(lv, rv.w, acc.w);
    }
    acc.x += (r == c0)     ? qdL[r] : 0.f;
    acc.y += (r == c0 + 1) ? qdL[r] : 0.f;
    acc.z += (r == c0 + 2) ? qdL[r] : 0.f;
    acc.w += (r == c0 + 3) ? qdL[r] : 0.f;
    *(float4*)&pL[r][c0] = acc;
    __syncthreads();

    const size_t obase = ((size_t)(b * TT + t)) << 10;
    if (g) {
      // R3: wave 0 inverts M = P + Cinv fully in registers (Jordan exchange)
      if (tid < 64) {
        float a[16];
#pragma unroll
        for (int c = 0; c < 16; ++c)
          a[c] = pL[rr][(hh << 4) + c] + ciL[rr][(hh << 4) + c];
        const int hs = hh << 5;
#pragma unroll 1
        for (int kk = 0; kk < 2; ++kk) {
          const int khs = kk << 5;
#pragma unroll
          for (int kc = 0; kc < 16; ++kc) {
            const int k = (kk << 4) | kc;
            float pv = __shfl(a[kc], khs | k, 64);
            float ip = 1.0f / pv;
            bool myrow = (rr == k);
            bool myh = (hh == kk);
#pragma unroll
            for (int c = 0; c < 16; ++c) {
              float sc = -a[c] * ip;
              bool isdiag = myh && (c == kc);
              a[c] = (myrow && !isdiag) ? sc : a[c];
            }
            float fk = __shfl(a[kc], khs | rr, 64);
#pragma unroll
            for (int c = 0; c < 16; ++c) {
              float prv = __shfl(a[c], hs | k, 64);
              bool pivcol = myh && (c == kc);
              float upd = fmaf(fk, prv, a[c]);
              a[c] = (!myrow && !pivcol) ? upd : a[c];
            }
            float cv = myrow ? ip : fk * ip;
            a[kc] = myh ? cv : a[kc];
          }
        }
#pragma unroll
        for (int c = 0; c < 16; ++c) wL[rr][(hh << 4) + c] = a[c];
      }
      __syncthreads();
      // R4: t2 = P @ W   (into t1L)
      acc.x = acc.y = acc.z = acc.w = 0.f;
#pragma unroll
      for (int k = 0; k < 32; ++k) {
        float lv = pL[r][k];
        float4 rv = *(const float4*)&wL[k][c0];
        acc.x = fmaf(lv, rv.x, acc.x); acc.y = fmaf(lv, rv.y, acc.y);
        acc.z = fmaf(lv, rv.z, acc.z); acc.w = fmaf(lv, rv.w, acc.w);
      }
      *(float4*)&t1L[r][c0] = acc;
      __syncthreads();
      // R5: Su = t2 @ Cinv ; Sigma_out = a3*Su + (1-a3)*P
      acc.x = acc.y = acc.z = acc.w = 0.f;
#pragma unroll
      for (int k = 0; k < 32; ++k) {
        float lv = t1L[r][k];
        float4 rv = *(const float4*)&ciL[k][c0];
        acc.x = fmaf(lv, rv.x, acc.x); acc.y = fmaf(lv, rv.y, acc.y);
        acc.z = fmaf(lv, rv.z, acc.z); acc.w = fmaf(lv, rv.w, acc.w);
      }
      float4 pv4 = *(const float4*)&pL[r][c0];
      float om = 1.0f - a3;
      float4 sg;
      sg.x = a3 * acc.x + om * pv4.x; sg.y = a3 * acc.y + om * pv4.y;
      sg.z = a3 * acc.z + om * pv4.z; sg.w = a3 * acc.w + om * pv4.w;
      *(float4*)&sigL[r][c0] = sg;
      *(float4*)(su_ws + obase + r * 32 + c0) = acc;
      *(float4*)(covs + obase + r * 32 + c0) = sg;
      __syncthreads();
    } else {
      float4 pv4 = *(const float4*)&pL[r][c0];
      *(float4*)&sigL[r][c0] = pv4;
      *(float4*)(covs + obase + r * 32 + c0) = pv4;
      __syncthreads();
    }
  }
}

// ---------- Phase 3: fused positions->corr copy + diag-block blend ----------
__global__ __launch_bounds__(256) void k_corr(const float* __restrict__ pos,
                                              const float* __restrict__ zws,
                                              const float* __restrict__ probs_out,
                                              const int* __restrict__ gate,
                                              const float* __restrict__ Hw,
                                              const float* __restrict__ htr,
                                              const float* __restrict__ su_ws,
                                              float* __restrict__ corr) {
  const int bid = blockIdx.x;
  const int b = bid >> 11, t = bid & 2047;
  const size_t pbase = ((size_t)bid) << 12;
  const float* src = pos + pbase;
  float* dst = corr + pbase;
  const int tid = threadIdx.x;
  const int g = gate[t];
  float4 v0 = ((const float4*)src)[tid];
  float4 v1 = ((const float4*)src)[256 + tid];
  float4 v2 = ((const float4*)src)[512 + tid];
  float4 v3 = ((const float4*)src)[768 + tid];
  if (!g) {
    ((float4*)dst)[tid] = v0;
    ((float4*)dst)[256 + tid] = v1;
    ((float4*)dst)[512 + tid] = v2;
    ((float4*)dst)[768 + tid] = v3;
    return;
  }
  __shared__ float muL[32], yL[64], vL[32], blL[32][4];
  float a4 = probs_out[b * TT + t];
  float p00 = 0.f, p01 = 0.f, p10 = 0.f, p11 = 0.f, mu = 0.f;
  if (tid < 32) {
    int ii = tid;
    p00 = src[(2 * ii) * 64 + 2 * ii];
    p01 = src[(2 * ii) * 64 + 2 * ii + 1];
    p10 = src[(2 * ii + 1) * 64 + 2 * ii];
    p11 = src[(2 * ii + 1) * 64 + 2 * ii + 1];
    mu = atan2f(p10, p00);
    muL[ii] = mu;
  }
  __syncthreads();
  if (tid < 64) {
    int o = tid;
    float zo = zws[((size_t)bid) * 64 + o];
    const float4* hrow = (const float4*)(Hw + o * 32);
    float s = 0.f;
#pragma unroll
    for (int i4 = 0; i4 < 8; ++i4) {
      float4 hv = hrow[i4];
      s += muL[i4 * 4] * hv.x + muL[i4 * 4 + 1] * hv.y +
           muL[i4 * 4 + 2] * hv.z + muL[i4 * 4 + 3] * hv.w;
    }
    yL[o] = zo - s;
  }
  __syncthreads();
  if (tid < 32) {
    const float4* hr = (const float4*)(htr + tid * 64);
    float s = 0.f;
#pragma unroll
    for (int j4 = 0; j4 < 16; ++j4) {
      float4 hv = hr[j4];
      s += yL[j4 * 4] * hv.x + yL[j4 * 4 + 1] * hv.y +
           yL[j4 * 4 + 2] * hv.z + yL[j4 * 4 + 3] * hv.w;
    }
    vL[tid] = s;
  }
  __syncthreads();
  if (tid < 32) {
    const float4* srow = (const float4*)(su_ws + (((size_t)bid) << 10) + tid * 32);
    float s = 0.f;
#pragma unroll
    for (int j4 = 0; j4 < 8; ++j4) {
      float4 sv = srow[j4];
      s += vL[j4 * 4] * sv.x + vL[j4 * 4 + 1] * sv.y +
           vL[j4 * 4 + 2] * sv.z + vL[j4 * 4 + 3] * sv.w;
    }
    float mc = mu + s;
    float cc = cosf(mc), sn = sinf(mc);
    float om = 1.0f - a4;
    blL[tid][0] = a4 * cc + om * p00;
    blL[tid][1] = a4 * (-sn) + om * p01;
    blL[tid][2] = a4 * sn + om * p10;
    blL[tid][3] = a4 * cc + om * p11;
  }
  __syncthreads();
  // substitute diag 2x2 blocks and store
  {
    float4 vv[4] = {v0, v1, v2, v3};
#pragma unroll
    for (int k = 0; k < 4; ++k) {
      int e0 = (k * 256 + tid) * 4;
      int row = e0 >> 6;
      int ii = row >> 1;
      int rp = (row & 1) << 1;
      int col = e0 & 63;
      float* f = (float*)&vv[k];
#pragma unroll
      for (int j = 0; j < 4; ++j) {
        int c = col + j;
        if ((c >> 1) == ii) f[j] = blL[ii][rp | (c & 1)];
      }
      ((float4*)dst)[k * 256 + tid] = vv[k];
    }
  }
}

extern "C" void kernel_launch(void* const* d_in, const int* in_sizes, int n_in,
                              void* d_out, int out_size, void* d_ws, size_t ws_size,
                              hipStream_t stream) {
  const float* pos  = (const float*)d_in[0];
  const float* emb  = (const float*)d_in[1];
  const float* Fg   = (const float*)d_in[2];
  const float* logQ = (const float*)d_in[3];
  const float* logR = (const float*)d_in[4];
  const float* Hw   = (const float*)d_in[5];
  const float* w1   = (const float*)d_in[6];
  const float* b1   = (const float*)d_in[7];
  const float* w2   = (const float*)d_in[8];
  const float* b2   = (const float*)d_in[9];
  const float* ow   = (const float*)d_in[10];
  const float* ob   = (const float*)d_in[11];

  float* corr  = (float*)d_out;
  float* covs  = corr + 67108864;   // B*T*64*64
  float* probs = corr + 83886080;   // + B*T*32*32

  float* ws   = (float*)d_ws;
  float* zws  = ws;                  // 1048576 floats
  int*   gate = (int*)(ws + 1048576);  // 2048 ints
  float* cinv = ws + 1050624;        // 1024
  float* htr  = ws + 1051648;        // 2048
  float* su   = ws + 1053696;        // 16777216

  hipLaunchKernelGGL(k_setup, dim3(1), dim3(256), 0, stream, Hw, logR, cinv, htr);
  hipLaunchKernelGGL(k_obs, dim3(4096), dim3(256), 0, stream, emb, w1, b1, w2, b2, ow, ob, probs, zws);
  hipLaunchKernelGGL(k_gate, dim3(8), dim3(256), 0, stream, probs, gate);
  hipLaunchKernelGGL(k_scan, dim3(8), dim3(256), 0, stream, Fg, logQ, probs, gate, cinv, covs, su);
  hipLaunchKernelGGL(k_corr, dim3(16384), dim3(256), 0, stream, pos, zws, probs, gate, Hw, htr, su, corr);
}

// Round 2
// 18869.861 us; speedup vs baseline: 1.0748x; 1.0748x over previous
//
#include <hip/hip_runtime.h>
#include <math.h>

#define TT 2048
#define NB 8

typedef __attribute__((ext_vector_type(16))) float f32x16;
typedef __attribute__((ext_vector_type(8))) __bf16 bf16x8;

// ---------- bf16 split helpers (truncation; residual captured by lo term) ----
__device__ __forceinline__ unsigned bfpack(float a, float b) {
  unsigned ua = __builtin_bit_cast(unsigned, a);
  unsigned ub = __builtin_bit_cast(unsigned, b);
  return (ua >> 16) | (ub & 0xFFFF0000u);
}
__device__ __forceinline__ float bfhi(float a) {
  unsigned ua = __builtin_bit_cast(unsigned, a) & 0xFFFF0000u;
  return __builtin_bit_cast(float, ua);
}

struct Frags { bf16x8 h0, l0, h1, l1; };

__device__ __forceinline__ bf16x8 packh(const float* x) {
  union { unsigned u[4]; bf16x8 v; } r;
#pragma unroll
  for (int d = 0; d < 4; ++d) r.u[d] = bfpack(x[2 * d], x[2 * d + 1]);
  return r.v;
}
__device__ __forceinline__ bf16x8 packl(const float* x) {
  union { unsigned u[4]; bf16x8 v; } r;
#pragma unroll
  for (int d = 0; d < 4; ++d)
    r.u[d] = bfpack(x[2 * d] - bfhi(x[2 * d]), x[2 * d + 1] - bfhi(x[2 * d + 1]));
  return r.v;
}
__device__ __forceinline__ Frags mk(const float* x) {
  Frags f;
  f.h0 = packh(x);     f.l0 = packl(x);
  f.h1 = packh(x + 8); f.l1 = packl(x + 8);
  return f;
}

// D = A*B with 3-term bf16 emulation (hi*hi + hi*lo + lo*hi), K=32 as 2 halves
__device__ __forceinline__ f32x16 mm3(const Frags& A, const Frags& B) {
  f32x16 a0 = {}, a1 = {};
  a0 = __builtin_amdgcn_mfma_f32_32x32x16_bf16(A.h0, B.h0, a0, 0, 0, 0);
  a0 = __builtin_amdgcn_mfma_f32_32x32x16_bf16(A.h0, B.l0, a0, 0, 0, 0);
  a0 = __builtin_amdgcn_mfma_f32_32x32x16_bf16(A.l0, B.h0, a0, 0, 0, 0);
  a1 = __builtin_amdgcn_mfma_f32_32x32x16_bf16(A.h1, B.h1, a1, 0, 0, 0);
  a1 = __builtin_amdgcn_mfma_f32_32x32x16_bf16(A.h1, B.l1, a1, 0, 0, 0);
  a1 = __builtin_amdgcn_mfma_f32_32x32x16_bf16(A.l1, B.h1, a1, 0, 0, 0);
  return a0 + a1;
}

// ---------- Phase 0: Cinv = (H^T R^-1 H)^-1 (32x32), HtRinv (32x64) ----------
__global__ __launch_bounds__(256) void k_setup(const float* __restrict__ Hw,
                                               const float* __restrict__ logR,
                                               float* __restrict__ cinv,
                                               float* __restrict__ htr) {
  __shared__ float C[32][33];
  __shared__ float rinv[64];
  int tid = threadIdx.x;
  if (tid < 64) rinv[tid] = expf(-logR[tid]);
  __syncthreads();
  int i = tid >> 3, j0 = (tid & 7) << 2;
  float a0 = 0.f, a1 = 0.f, a2 = 0.f, a3 = 0.f;
  for (int o = 0; o < 64; ++o) {
    float hio = Hw[o * 32 + i] * rinv[o];
    a0 += hio * Hw[o * 32 + j0];
    a1 += hio * Hw[o * 32 + j0 + 1];
    a2 += hio * Hw[o * 32 + j0 + 2];
    a3 += hio * Hw[o * 32 + j0 + 3];
  }
  C[i][j0] = a0; C[i][j0 + 1] = a1; C[i][j0 + 2] = a2; C[i][j0 + 3] = a3;
  for (int e = 0; e < 8; ++e) {
    int idx = tid * 8 + e;
    int ii = idx >> 6, o = idx & 63;
    htr[idx] = Hw[o * 32 + ii] * rinv[o];
  }
  __syncthreads();
  for (int k = 0; k < 32; ++k) {
    float ip = 1.0f / C[k][k];
    __syncthreads();
    if (tid < 32 && tid != k) C[k][tid] = -C[k][tid] * ip;
    __syncthreads();
    if (i != k) {
      float f = C[i][k];
      for (int q = 0; q < 4; ++q) {
        int j = j0 + q;
        if (j != k) C[i][j] += f * C[k][j];
      }
    }
    __syncthreads();
    if (tid < 32) {
      if (tid == k) C[k][k] = ip; else C[tid][k] *= ip;
    }
    __syncthreads();
  }
  cinv[i * 32 + j0]     = C[i][j0];
  cinv[i * 32 + j0 + 1] = C[i][j0 + 1];
  cinv[i * 32 + j0 + 2] = C[i][j0 + 2];
  cinv[i * 32 + j0 + 3] = C[i][j0 + 3];
}

// ---------- Phase 1: probs (B,T) and z = emb @ obs_w^T + obs_b ----------
__global__ __launch_bounds__(256) void k_obs(const float* __restrict__ emb,
                                             const float* __restrict__ w1,
                                             const float* __restrict__ b1,
                                             const float* __restrict__ w2,
                                             const float* __restrict__ b2,
                                             const float* __restrict__ ow,
                                             const float* __restrict__ ob,
                                             float* __restrict__ probs_out,
                                             float* __restrict__ zws) {
  int wave = threadIdx.x >> 6, lane = threadIdx.x & 63;
  int row = blockIdx.x * 4 + wave;
  float xv = emb[(size_t)row * 64 + lane];
  const float4* w1v = (const float4*)(w1 + lane * 64);
  float hacc = b1[lane];
#pragma unroll
  for (int i4 = 0; i4 < 16; ++i4) {
    float4 wv = w1v[i4];
    hacc += __shfl(xv, i4 * 4, 64) * wv.x + __shfl(xv, i4 * 4 + 1, 64) * wv.y +
            __shfl(xv, i4 * 4 + 2, 64) * wv.z + __shfl(xv, i4 * 4 + 3, 64) * wv.w;
  }
  float h = fmaxf(hacc, 0.f);
  float s = h * w2[lane];
#pragma unroll
  for (int off = 32; off; off >>= 1) s += __shfl_xor(s, off, 64);
  float prob = 1.0f / (1.0f + expf(-(s + b2[0])));
  if (lane == 0) probs_out[row] = prob;
  const float4* owv = (const float4*)(ow + lane * 64);
  float zacc = ob[lane];
#pragma unroll
  for (int i4 = 0; i4 < 16; ++i4) {
    float4 wv = owv[i4];
    zacc += __shfl(xv, i4 * 4, 64) * wv.x + __shfl(xv, i4 * 4 + 1, 64) * wv.y +
            __shfl(xv, i4 * 4 + 2, 64) * wv.z + __shfl(xv, i4 * 4 + 3, 64) * wv.w;
  }
  zws[(size_t)row * 64 + lane] = zacc;
}

// ---------- Phase 1b: gate[t] = any_b(probs[b][t] > 0.5) ----------
__global__ void k_gate(const float* __restrict__ probs_out, int* __restrict__ gate) {
  int t = blockIdx.x * 256 + threadIdx.x;
  if (t < TT) {
    int g = 0;
    for (int b = 0; b < NB; ++b) g |= (probs_out[b * TT + t] > 0.5f) ? 1 : 0;
    gate[t] = g;
  }
}

// ---------- Phase 2: Riccati scan — ONE WAVE per batch, all-register MFMA ----
// C/D layout: lane l=(c=l&31, hh=l>>5), reg q -> element (row,col)=(rq,c),
// rq = (q&3)+8*(q>>2)+4*hh.  Operand slot map (shared by A and B fills):
// slot i, half s  <->  C/D reg q = i+8s  (bijective => layout-robust).
__global__ __launch_bounds__(64) void k_scan2(const float* __restrict__ Fg,
                                              const float* __restrict__ logQ,
                                              const float* __restrict__ probs_out,
                                              const int* __restrict__ gate,
                                              const float* __restrict__ cinv,
                                              float* __restrict__ covs,
                                              float* __restrict__ su_ws) {
  __shared__ float probL[TT];
  __shared__ int gateL[TT];
  const int b = blockIdx.x, l = threadIdx.x;
  const int hh = l >> 5, c = l & 31;

  for (int i = l; i < TT / 4; i += 64) {
    ((float4*)probL)[i] = ((const float4*)(probs_out + (size_t)b * TT))[i];
    ((int4*)gateL)[i] = ((const int4*)gate)[i];
  }

  // Constant operand fragments: F (A-frag == B-frag of F^T), Cinv (A-frag)
  float fFv[16], fCv[16];
#pragma unroll
  for (int s = 0; s < 2; ++s)
#pragma unroll
    for (int i = 0; i < 8; ++i) {
      int col = 16 * s + 4 * hh + (i & 3) + 8 * (i >> 2);
      fFv[i + 8 * s] = Fg[c * 32 + col];
      fCv[i + 8 * s] = cinv[c * 32 + col];
    }
  Frags Ff = mk(fFv);
  Frags Cf = mk(fCv);

  float ci[16], qd[16], sig[16];
#pragma unroll
  for (int q = 0; q < 16; ++q) {
    int rq = (q & 3) + 8 * (q >> 2) + 4 * hh;
    ci[q] = cinv[rq * 32 + c];
    qd[q] = (rq == c) ? expf(logQ[c]) : 0.0f;
    sig[q] = (rq == c) ? 0.01f : 0.0f;
  }

  float* cb = covs + (((size_t)b * TT) << 10) + c;
  float* sb = su_ws + (((size_t)b * TT) << 10) + c;

#pragma unroll 1
  for (int t = 0; t < TT; ++t) {
    const float a3 = probL[t];
    const int g = gateL[t];

    // G2 = Sigma * F^T   (A = Sigma via symmetry, B = F^T == Ff)
    Frags Sf = mk(sig);
    f32x16 accG = mm3(Sf, Ff);
    float g2[16];
#pragma unroll
    for (int q = 0; q < 16; ++q) g2[q] = accG[q];

    // P = F * G2 + diag(Qd)
    Frags Gf = mk(g2);
    f32x16 accP = mm3(Ff, Gf);
    float p[16];
#pragma unroll
    for (int q = 0; q < 16; ++q) p[q] = accP[q] + qd[q];

    if (g) {
      // M = P + Cinv ; W = M^-1 via in-register Jordan exchange (C/D layout,
      // lanes act as pretend-rows by symmetry)
      float m[16];
#pragma unroll
      for (int q = 0; q < 16; ++q) m[q] = p[q] + ci[q];

#pragma unroll
      for (int k = 0; k < 32; ++k) {
        const int hk = (k >> 2) & 1;
        const int qk = (k & 3) | ((k >> 3) << 2);
        float pv = __shfl(m[qk], k + 32 * hk, 64);
        float r0 = __builtin_amdgcn_rcpf(pv);
        float ip = r0 * (2.0f - pv * r0);
        const bool myrow = (c == k);
        // scale pretend-row k (negative), except the pivot element
#pragma unroll
        for (int q = 0; q < 16; ++q) {
          bool isdiag = (q == qk) && (hh == hk);
          float sc = -m[q] * ip;
          m[q] = (myrow && !isdiag) ? sc : m[q];
        }
        // fk = M[c][k] (old column-k value; source lanes untouched by scale)
        float fk = __shfl(m[qk], c + 32 * hk, 64);
        // prv[q] = scaled row-k value at this lane's pretend-col
        float prv[16];
#pragma unroll
        for (int q = 0; q < 16; ++q) prv[q] = __shfl(m[q], k + 32 * hh, 64);
        // rank-1 update (skip pivot row and pivot column)
#pragma unroll
        for (int q = 0; q < 16; ++q) {
          bool pivcol = (q == qk) && (hh == hk);
          float upd = fmaf(fk, prv[q], m[q]);
          m[q] = (!myrow && !pivcol) ? upd : m[q];
        }
        // column-k fixup
        float cf = myrow ? ip : fk * ip;
        m[qk] = (hh == hk) ? cf : m[qk];
      }

      // Y = W * P  (A = W via symmetry, B = P)
      Frags Wf = mk(m);
      Frags Pf = mk(p);
      f32x16 accY = mm3(Wf, Pf);
      float y[16];
#pragma unroll
      for (int q = 0; q < 16; ++q) y[q] = accY[q];

      // Su = Cinv * Y
      Frags Yf = mk(y);
      f32x16 accS = mm3(Cf, Yf);

      const float om = 1.0f - a3;
#pragma unroll
      for (int q = 0; q < 16; ++q) {
        int rq = (q & 3) + 8 * (q >> 2) + 4 * hh;
        float su = accS[q];
        float sg = a3 * su + om * p[q];
        sig[q] = sg;
        cb[rq * 32] = sg;
        sb[rq * 32] = su;
      }
    } else {
#pragma unroll
      for (int q = 0; q < 16; ++q) {
        int rq = (q & 3) + 8 * (q >> 2) + 4 * hh;
        sig[q] = p[q];
        cb[rq * 32] = p[q];
      }
    }
    cb += 1024;
    sb += 1024;
  }
}

// ---------- Phase 3: fused positions->corr copy + diag-block blend ----------
__global__ __launch_bounds__(256) void k_corr(const float* __restrict__ pos,
                                              const float* __restrict__ zws,
                                              const float* __restrict__ probs_out,
                                              const int* __restrict__ gate,
                                              const float* __restrict__ Hw,
                                              const float* __restrict__ htr,
                                              const float* __restrict__ su_ws,
                                              float* __restrict__ corr) {
  const int bid = blockIdx.x;
  const int b = bid >> 11, t = bid & 2047;
  const size_t pbase = ((size_t)bid) << 12;
  const float* src = pos + pbase;
  float* dst = corr + pbase;
  const int tid = threadIdx.x;
  const int g = gate[t];
  float4 v0 = ((const float4*)src)[tid];
  float4 v1 = ((const float4*)src)[256 + tid];
  float4 v2 = ((const float4*)src)[512 + tid];
  float4 v3 = ((const float4*)src)[768 + tid];
  if (!g) {
    ((float4*)dst)[tid] = v0;
    ((float4*)dst)[256 + tid] = v1;
    ((float4*)dst)[512 + tid] = v2;
    ((float4*)dst)[768 + tid] = v3;
    return;
  }
  __shared__ float muL[32], yL[64], vL[32], blL[32][4];
  float a4 = probs_out[b * TT + t];
  float p00 = 0.f, p01 = 0.f, p10 = 0.f, p11 = 0.f, mu = 0.f;
  if (tid < 32) {
    int ii = tid;
    p00 = src[(2 * ii) * 64 + 2 * ii];
    p01 = src[(2 * ii) * 64 + 2 * ii + 1];
    p10 = src[(2 * ii + 1) * 64 + 2 * ii];
    p11 = src[(2 * ii + 1) * 64 + 2 * ii + 1];
    mu = atan2f(p10, p00);
    muL[ii] = mu;
  }
  __syncthreads();
  if (tid < 64) {
    int o = tid;
    float zo = zws[((size_t)bid) * 64 + o];
    const float4* hrow = (const float4*)(Hw + o * 32);
    float s = 0.f;
#pragma unroll
    for (int i4 = 0; i4 < 8; ++i4) {
      float4 hv = hrow[i4];
      s += muL[i4 * 4] * hv.x + muL[i4 * 4 + 1] * hv.y +
           muL[i4 * 4 + 2] * hv.z + muL[i4 * 4 + 3] * hv.w;
    }
    yL[o] = zo - s;
  }
  __syncthreads();
  if (tid < 32) {
    const float4* hr = (const float4*)(htr + tid * 64);
    float s = 0.f;
#pragma unroll
    for (int j4 = 0; j4 < 16; ++j4) {
      float4 hv = hr[j4];
      s += yL[j4 * 4] * hv.x + yL[j4 * 4 + 1] * hv.y +
           yL[j4 * 4 + 2] * hv.z + yL[j4 * 4 + 3] * hv.w;
    }
    vL[tid] = s;
  }
  __syncthreads();
  if (tid < 32) {
    const float4* srow = (const float4*)(su_ws + (((size_t)bid) << 10) + tid * 32);
    float s = 0.f;
#pragma unroll
    for (int j4 = 0; j4 < 8; ++j4) {
      float4 sv = srow[j4];
      s += vL[j4 * 4] * sv.x + vL[j4 * 4 + 1] * sv.y +
           vL[j4 * 4 + 2] * sv.z + vL[j4 * 4 + 3] * sv.w;
    }
    float mc = mu + s;
    float cc = cosf(mc), sn = sinf(mc);
    float om = 1.0f - a4;
    blL[tid][0] = a4 * cc + om * p00;
    blL[tid][1] = a4 * (-sn) + om * p01;
    blL[tid][2] = a4 * sn + om * p10;
    blL[tid][3] = a4 * cc + om * p11;
  }
  __syncthreads();
  {
    float4 vv[4] = {v0, v1, v2, v3};
#pragma unroll
    for (int k = 0; k < 4; ++k) {
      int e0 = (k * 256 + tid) * 4;
      int row = e0 >> 6;
      int ii = row >> 1;
      int rp = (row & 1) << 1;
      int col = e0 & 63;
      float* f = (float*)&vv[k];
#pragma unroll
      for (int j = 0; j < 4; ++j) {
        int cc2 = col + j;
        if ((cc2 >> 1) == ii) f[j] = blL[ii][rp | (cc2 & 1)];
      }
      ((float4*)dst)[k * 256 + tid] = vv[k];
    }
  }
}

extern "C" void kernel_launch(void* const* d_in, const int* in_sizes, int n_in,
                              void* d_out, int out_size, void* d_ws, size_t ws_size,
                              hipStream_t stream) {
  const float* pos  = (const float*)d_in[0];
  const float* emb  = (const float*)d_in[1];
  const float* Fg   = (const float*)d_in[2];
  const float* logQ = (const float*)d_in[3];
  const float* logR = (const float*)d_in[4];
  const float* Hw   = (const float*)d_in[5];
  const float* w1   = (const float*)d_in[6];
  const float* b1   = (const float*)d_in[7];
  const float* w2   = (const float*)d_in[8];
  const float* b2   = (const float*)d_in[9];
  const float* ow   = (const float*)d_in[10];
  const float* ob   = (const float*)d_in[11];

  float* corr  = (float*)d_out;
  float* covs  = corr + 67108864;   // B*T*64*64
  float* probs = corr + 83886080;   // + B*T*32*32

  float* ws   = (float*)d_ws;
  float* zws  = ws;                    // 1048576 floats
  int*   gate = (int*)(ws + 1048576);  // 2048 ints
  float* cinv = ws + 1050624;          // 1024
  float* htr  = ws + 1051648;          // 2048
  float* su   = ws + 1053696;          // 16777216

  hipLaunchKernelGGL(k_setup, dim3(1), dim3(256), 0, stream, Hw, logR, cinv, htr);
  hipLaunchKernelGGL(k_obs, dim3(4096), dim3(256), 0, stream, emb, w1, b1, w2, b2, ow, ob, probs, zws);
  hipLaunchKernelGGL(k_gate, dim3(8), dim3(256), 0, stream, probs, gate);
  hipLaunchKernelGGL(k_scan2, dim3(8), dim3(64), 0, stream, Fg, logQ, probs, gate, cinv, covs, su);
  hipLaunchKernelGGL(k_corr, dim3(16384), dim3(256), 0, stream, pos, zws, probs, gate, Hw, htr, su, corr);
}

// Round 3
// 7471.747 us; speedup vs baseline: 2.7144x; 2.5255x over previous
//
#include <hip/hip_runtime.h>
#include <math.h>

#define TT 2048
#define NB 8

typedef __attribute__((ext_vector_type(16))) float f32x16;
typedef __attribute__((ext_vector_type(8))) __bf16 bf16x8;

// ---------- bf16 split helpers (RNE hi via hw cvt; residual lo) -------------
__device__ __forceinline__ bf16x8 packh(const float* x) {
  bf16x8 v;
#pragma unroll
  for (int d = 0; d < 8; ++d) v[d] = (__bf16)x[d];
  return v;
}
__device__ __forceinline__ bf16x8 packl(const float* x) {
  bf16x8 v;
#pragma unroll
  for (int d = 0; d < 8; ++d) v[d] = (__bf16)(x[d] - (float)((__bf16)x[d]));
  return v;
}

struct Frags { bf16x8 h0, l0, h1, l1; };
struct FragsH { bf16x8 h0, h1; };

__device__ __forceinline__ Frags mk(const float* x) {
  Frags f;
  f.h0 = packh(x);     f.l0 = packl(x);
  f.h1 = packh(x + 8); f.l1 = packl(x + 8);
  return f;
}
__device__ __forceinline__ FragsH mkh(const float* x) {
  FragsH f;
  f.h0 = packh(x);
  f.h1 = packh(x + 8);
  return f;
}

// D = A*B, 3-term bf16 emulation (hh + hl + lh), K=32 as 2 halves
__device__ __forceinline__ f32x16 mm3(const Frags& A, const Frags& B) {
  f32x16 a0 = {}, a1 = {}, b0 = {}, b1 = {};
  a0 = __builtin_amdgcn_mfma_f32_32x32x16_bf16(A.h0, B.h0, a0, 0, 0, 0);
  b0 = __builtin_amdgcn_mfma_f32_32x32x16_bf16(A.h0, B.l0, b0, 0, 0, 0);
  a0 = __builtin_amdgcn_mfma_f32_32x32x16_bf16(A.l0, B.h0, a0, 0, 0, 0);
  a1 = __builtin_amdgcn_mfma_f32_32x32x16_bf16(A.h1, B.h1, a1, 0, 0, 0);
  b1 = __builtin_amdgcn_mfma_f32_32x32x16_bf16(A.h1, B.l1, b1, 0, 0, 0);
  a1 = __builtin_amdgcn_mfma_f32_32x32x16_bf16(A.l1, B.h1, a1, 0, 0, 0);
  return (a0 + b0) + (a1 + b1);
}
// cheap 1-term (hi only) product
__device__ __forceinline__ f32x16 mm1(bf16x8 A0, bf16x8 A1, bf16x8 B0, bf16x8 B1) {
  f32x16 a0 = {}, a1 = {};
  a0 = __builtin_amdgcn_mfma_f32_32x32x16_bf16(A0, B0, a0, 0, 0, 0);
  a1 = __builtin_amdgcn_mfma_f32_32x32x16_bf16(A1, B1, a1, 0, 0, 0);
  return a0 + a1;
}
// transpose: (stored Z as A) x (exact identity as B) = Z^T ; 4 MFMAs
__device__ __forceinline__ f32x16 mmT(const Frags& A, const FragsH& Id) {
  f32x16 a0 = {}, a1 = {};
  a0 = __builtin_amdgcn_mfma_f32_32x32x16_bf16(A.h0, Id.h0, a0, 0, 0, 0);
  a0 = __builtin_amdgcn_mfma_f32_32x32x16_bf16(A.l0, Id.h0, a0, 0, 0, 0);
  a1 = __builtin_amdgcn_mfma_f32_32x32x16_bf16(A.h1, Id.h1, a1, 0, 0, 0);
  a1 = __builtin_amdgcn_mfma_f32_32x32x16_bf16(A.l1, Id.h1, a1, 0, 0, 0);
  return a0 + a1;
}

// ---------- Phase 0: Cinv = (H^T R^-1 H)^-1 (32x32), HtRinv (32x64) ----------
__global__ __launch_bounds__(256) void k_setup(const float* __restrict__ Hw,
                                               const float* __restrict__ logR,
                                               float* __restrict__ cinv,
                                               float* __restrict__ htr) {
  __shared__ float C[32][33];
  __shared__ float rinv[64];
  int tid = threadIdx.x;
  if (tid < 64) rinv[tid] = expf(-logR[tid]);
  __syncthreads();
  int i = tid >> 3, j0 = (tid & 7) << 2;
  float a0 = 0.f, a1 = 0.f, a2 = 0.f, a3 = 0.f;
  for (int o = 0; o < 64; ++o) {
    float hio = Hw[o * 32 + i] * rinv[o];
    a0 += hio * Hw[o * 32 + j0];
    a1 += hio * Hw[o * 32 + j0 + 1];
    a2 += hio * Hw[o * 32 + j0 + 2];
    a3 += hio * Hw[o * 32 + j0 + 3];
  }
  C[i][j0] = a0; C[i][j0 + 1] = a1; C[i][j0 + 2] = a2; C[i][j0 + 3] = a3;
  for (int e = 0; e < 8; ++e) {
    int idx = tid * 8 + e;
    int ii = idx >> 6, o = idx & 63;
    htr[idx] = Hw[o * 32 + ii] * rinv[o];
  }
  __syncthreads();
  for (int k = 0; k < 32; ++k) {
    float ip = 1.0f / C[k][k];
    __syncthreads();
    if (tid < 32 && tid != k) C[k][tid] = -C[k][tid] * ip;
    __syncthreads();
    if (i != k) {
      float f = C[i][k];
      for (int q = 0; q < 4; ++q) {
        int j = j0 + q;
        if (j != k) C[i][j] += f * C[k][j];
      }
    }
    __syncthreads();
    if (tid < 32) {
      if (tid == k) C[k][k] = ip; else C[tid][k] *= ip;
    }
    __syncthreads();
  }
  cinv[i * 32 + j0]     = C[i][j0];
  cinv[i * 32 + j0 + 1] = C[i][j0 + 1];
  cinv[i * 32 + j0 + 2] = C[i][j0 + 2];
  cinv[i * 32 + j0 + 3] = C[i][j0 + 3];
}

// ---------- Phase 1: probs (B,T) and z = emb @ obs_w^T + obs_b ----------
__global__ __launch_bounds__(256) void k_obs(const float* __restrict__ emb,
                                             const float* __restrict__ w1,
                                             const float* __restrict__ b1,
                                             const float* __restrict__ w2,
                                             const float* __restrict__ b2,
                                             const float* __restrict__ ow,
                                             const float* __restrict__ ob,
                                             float* __restrict__ probs_out,
                                             float* __restrict__ zws) {
  int wave = threadIdx.x >> 6, lane = threadIdx.x & 63;
  int row = blockIdx.x * 4 + wave;
  float xv = emb[(size_t)row * 64 + lane];
  const float4* w1v = (const float4*)(w1 + lane * 64);
  float hacc = b1[lane];
#pragma unroll
  for (int i4 = 0; i4 < 16; ++i4) {
    float4 wv = w1v[i4];
    hacc += __shfl(xv, i4 * 4, 64) * wv.x + __shfl(xv, i4 * 4 + 1, 64) * wv.y +
            __shfl(xv, i4 * 4 + 2, 64) * wv.z + __shfl(xv, i4 * 4 + 3, 64) * wv.w;
  }
  float h = fmaxf(hacc, 0.f);
  float s = h * w2[lane];
#pragma unroll
  for (int off = 32; off; off >>= 1) s += __shfl_xor(s, off, 64);
  float prob = 1.0f / (1.0f + expf(-(s + b2[0])));
  if (lane == 0) probs_out[row] = prob;
  const float4* owv = (const float4*)(ow + lane * 64);
  float zacc = ob[lane];
#pragma unroll
  for (int i4 = 0; i4 < 16; ++i4) {
    float4 wv = owv[i4];
    zacc += __shfl(xv, i4 * 4, 64) * wv.x + __shfl(xv, i4 * 4 + 1, 64) * wv.y +
            __shfl(xv, i4 * 4 + 2, 64) * wv.z + __shfl(xv, i4 * 4 + 3, 64) * wv.w;
  }
  zws[(size_t)row * 64 + lane] = zacc;
}

// ---------- Phase 1b: gate[t] = any_b(probs[b][t] > 0.5) ----------
__global__ void k_gate(const float* __restrict__ probs_out, int* __restrict__ gate) {
  int t = blockIdx.x * 256 + threadIdx.x;
  if (t < TT) {
    int g = 0;
    for (int b = 0; b < NB; ++b) g |= (probs_out[b * TT + t] > 0.5f) ? 1 : 0;
    gate[t] = g;
  }
}

// ---------- Phase 2: Riccati scan — one wave/batch, warm-started Newton ------
// C/D layout: lane l=(c=l&31, hh=l>>5), reg q -> (row rq, col c),
// rq=(q&3)+8*(q>>2)+4*hh. C/D-resident-as-A => multiplies as Z^T (use
// symmetric A only); C/D-resident-as-B => multiplies as Z. (validated R2)
__global__ __launch_bounds__(64, 1) void k_scan2(const float* __restrict__ Fg,
                                                 const float* __restrict__ logQ,
                                                 const float* __restrict__ probs_out,
                                                 const int* __restrict__ gate,
                                                 const float* __restrict__ cinv,
                                                 float* __restrict__ covs,
                                                 float* __restrict__ su_ws) {
  __shared__ float probL[TT];
  __shared__ int gateL[TT];
  const int b = blockIdx.x, l = threadIdx.x;
  const int hh = l >> 5, c = l & 31;

  for (int i = l; i < TT / 4; i += 64) {
    ((float4*)probL)[i] = ((const float4*)(probs_out + (size_t)b * TT))[i];
    ((int4*)gateL)[i] = ((const int4*)gate)[i];
  }

  // Constant fragments: F, Cinv (B-map load), exact identity (hi only)
  float fFv[16], fCv[16], fIv[16];
#pragma unroll
  for (int s = 0; s < 2; ++s)
#pragma unroll
    for (int i = 0; i < 8; ++i) {
      int col = 16 * s + 4 * hh + (i & 3) + 8 * (i >> 2);
      fFv[i + 8 * s] = Fg[c * 32 + col];
      fCv[i + 8 * s] = cinv[c * 32 + col];
      fIv[i + 8 * s] = (col == c) ? 1.0f : 0.0f;
    }
  Frags Ff = mk(fFv);
  Frags Cf = mk(fCv);
  FragsH Idf = mkh(fIv);

  float ci[16], qd[16], sig[16], X[16];
#pragma unroll
  for (int q = 0; q < 16; ++q) {
    int rq = (q & 3) + 8 * (q >> 2) + 4 * hh;
    ci[q] = cinv[rq * 32 + c];
    qd[q] = (rq == c) ? expf(logQ[c]) : 0.0f;
    sig[q] = (rq == c) ? 0.01f : 0.0f;
    X[q] = 0.0f;  // forces Jordan on first gated step
  }

  float* cb = covs + (((size_t)b * TT) << 10) + c;
  float* sb = su_ws + (((size_t)b * TT) << 10) + c;

#pragma unroll 1
  for (int t = 0; t < TT; ++t) {
    const float a3 = probL[t];
    const int g = gateL[t];

    // G2 = Sigma * F^T ; P = F * G2 + diag(Qd)
    Frags Sf = mk(sig);
    f32x16 accG = mm3(Sf, Ff);
    float g2[16];
#pragma unroll
    for (int q = 0; q < 16; ++q) g2[q] = accG[q];
    Frags Gf = mk(g2);
    f32x16 accP = mm3(Ff, Gf);
    float p[16];
#pragma unroll
    for (int q = 0; q < 16; ++q) p[q] = accP[q] + qd[q];

    if (g) {
      float m[16];
#pragma unroll
      for (int q = 0; q < 16; ++q) m[q] = p[q] + ci[q];
      Frags Mf = mk(m);

      // residual check with warm start X
      FragsH Xh = mkh(X);
      f32x16 T = mm1(Mf.h0, Mf.h1, Xh.h0, Xh.h1);
      float csum = 0.f;
#pragma unroll
      for (int q = 0; q < 16; ++q) {
        int rq = (q & 3) + 8 * (q >> 2) + 4 * hh;
        csum += fabsf(((rq == c) ? 1.0f : 0.0f) - T[q]);
      }
      csum += __shfl_xor(csum, 32);  // full |col sum| of E0

      if (__all(csum < 0.6f)) {
        // ---- Newton-Schulz: 3 cheap squaring stages + 1 exact ----
#pragma unroll
        for (int s = 0; s < 3; ++s) {
          float G[16];
#pragma unroll
          for (int q = 0; q < 16; ++q) {
            int rq = (q & 3) + 8 * (q >> 2) + 4 * hh;
            G[q] = ((rq == c) ? 2.0f : 0.0f) - T[q];
          }
          FragsH Gh = mkh(G);
          f32x16 Xn = mm1(Xh.h0, Xh.h1, Gh.h0, Gh.h1);  // X^T*G, X ~symmetric
#pragma unroll
          for (int q = 0; q < 16; ++q) X[q] = Xn[q];
          Xh = mkh(X);
          if (s < 2) T = mm1(Mf.h0, Mf.h1, Xh.h0, Xh.h1);
        }
        // symmetrize (kills accumulated antisymmetric error): X = (X+X^T)/2
        Frags Xf3 = mk(X);
        f32x16 Xt = mmT(Xf3, Idf);
#pragma unroll
        for (int q = 0; q < 16; ++q) X[q] = 0.5f * (X[q] + Xt[q]);
        // final exact stage
        Frags Xfs = mk(X);
        f32x16 T3 = mm3(Mf, Xfs);
        float G3[16];
#pragma unroll
        for (int q = 0; q < 16; ++q) {
          int rq = (q & 3) + 8 * (q >> 2) + 4 * hh;
          G3[q] = ((rq == c) ? 2.0f : 0.0f) - T3[q];
        }
        Frags Gf3 = mk(G3);
        f32x16 X4 = mm3(Xfs, Gf3);
#pragma unroll
        for (int q = 0; q < 16; ++q) X[q] = X4[q];
      } else {
        // ---- Jordan-exchange fallback (validated path, rare) ----
#pragma unroll
        for (int k = 0; k < 32; ++k) {
          const int hk = (k >> 2) & 1;
          const int qk = (k & 3) | ((k >> 3) << 2);
          float pv = __shfl(m[qk], k + 32 * hk, 64);
          float r0 = __builtin_amdgcn_rcpf(pv);
          float ip = r0 * (2.0f - pv * r0);
          const bool myrow = (c == k);
#pragma unroll
          for (int q = 0; q < 16; ++q) {
            bool isdiag = (q == qk) && (hh == hk);
            float sc = -m[q] * ip;
            m[q] = (myrow && !isdiag) ? sc : m[q];
          }
          float fk = __shfl(m[qk], c + 32 * hk, 64);
          float prv[16];
#pragma unroll
          for (int q = 0; q < 16; ++q) prv[q] = __shfl(m[q], k + 32 * hh, 64);
#pragma unroll
          for (int q = 0; q < 16; ++q) {
            bool pivcol = (q == qk) && (hh == hk);
            float upd = fmaf(fk, prv[q], m[q]);
            m[q] = (!myrow && !pivcol) ? upd : m[q];
          }
          float cf = myrow ? ip : fk * ip;
          m[qk] = (hh == hk) ? cf : m[qk];
        }
#pragma unroll
        for (int q = 0; q < 16; ++q) X[q] = m[q];
      }

      // Y = W * P ; Su = Cinv * Y
      Frags Wf = mk(X);
      Frags Pf = mk(p);
      f32x16 accY = mm3(Wf, Pf);
      float y[16];
#pragma unroll
      for (int q = 0; q < 16; ++q) y[q] = accY[q];
      Frags Yf = mk(y);
      f32x16 accS = mm3(Cf, Yf);

      const float om = 1.0f - a3;
#pragma unroll
      for (int q = 0; q < 16; ++q) {
        int rq = (q & 3) + 8 * (q >> 2) + 4 * hh;
        float su = accS[q];
        float sg = a3 * su + om * p[q];
        sig[q] = sg;
        cb[rq * 32] = sg;
        sb[rq * 32] = su;
      }
    } else {
#pragma unroll
      for (int q = 0; q < 16; ++q) {
        int rq = (q & 3) + 8 * (q >> 2) + 4 * hh;
        sig[q] = p[q];
        cb[rq * 32] = p[q];
      }
    }
    cb += 1024;
    sb += 1024;
  }
}

// ---------- Phase 3: fused positions->corr copy + diag-block blend ----------
__global__ __launch_bounds__(256) void k_corr(const float* __restrict__ pos,
                                              const float* __restrict__ zws,
                                              const float* __restrict__ probs_out,
                                              const int* __restrict__ gate,
                                              const float* __restrict__ Hw,
                                              const float* __restrict__ htr,
                                              const float* __restrict__ su_ws,
                                              float* __restrict__ corr) {
  const int bid = blockIdx.x;
  const int b = bid >> 11, t = bid & 2047;
  const size_t pbase = ((size_t)bid) << 12;
  const float* src = pos + pbase;
  float* dst = corr + pbase;
  const int tid = threadIdx.x;
  const int g = gate[t];
  float4 v0 = ((const float4*)src)[tid];
  float4 v1 = ((const float4*)src)[256 + tid];
  float4 v2 = ((const float4*)src)[512 + tid];
  float4 v3 = ((const float4*)src)[768 + tid];
  if (!g) {
    ((float4*)dst)[tid] = v0;
    ((float4*)dst)[256 + tid] = v1;
    ((float4*)dst)[512 + tid] = v2;
    ((float4*)dst)[768 + tid] = v3;
    return;
  }
  __shared__ float muL[32], yL[64], vL[32], blL[32][4];
  float a4 = probs_out[b * TT + t];
  float p00 = 0.f, p01 = 0.f, p10 = 0.f, p11 = 0.f, mu = 0.f;
  if (tid < 32) {
    int ii = tid;
    p00 = src[(2 * ii) * 64 + 2 * ii];
    p01 = src[(2 * ii) * 64 + 2 * ii + 1];
    p10 = src[(2 * ii + 1) * 64 + 2 * ii];
    p11 = src[(2 * ii + 1) * 64 + 2 * ii + 1];
    mu = atan2f(p10, p00);
    muL[ii] = mu;
  }
  __syncthreads();
  if (tid < 64) {
    int o = tid;
    float zo = zws[((size_t)bid) * 64 + o];
    const float4* hrow = (const float4*)(Hw + o * 32);
    float s = 0.f;
#pragma unroll
    for (int i4 = 0; i4 < 8; ++i4) {
      float4 hv = hrow[i4];
      s += muL[i4 * 4] * hv.x + muL[i4 * 4 + 1] * hv.y +
           muL[i4 * 4 + 2] * hv.z + muL[i4 * 4 + 3] * hv.w;
    }
    yL[o] = zo - s;
  }
  __syncthreads();
  if (tid < 32) {
    const float4* hr = (const float4*)(htr + tid * 64);
    float s = 0.f;
#pragma unroll
    for (int j4 = 0; j4 < 16; ++j4) {
      float4 hv = hr[j4];
      s += yL[j4 * 4] * hv.x + yL[j4 * 4 + 1] * hv.y +
           yL[j4 * 4 + 2] * hv.z + yL[j4 * 4 + 3] * hv.w;
    }
    vL[tid] = s;
  }
  __syncthreads();
  if (tid < 32) {
    const float4* srow = (const float4*)(su_ws + (((size_t)bid) << 10) + tid * 32);
    float s = 0.f;
#pragma unroll
    for (int j4 = 0; j4 < 8; ++j4) {
      float4 sv = srow[j4];
      s += vL[j4 * 4] * sv.x + vL[j4 * 4 + 1] * sv.y +
           vL[j4 * 4 + 2] * sv.z + vL[j4 * 4 + 3] * sv.w;
    }
    float mc = mu + s;
    float cc = cosf(mc), sn = sinf(mc);
    float om = 1.0f - a4;
    blL[tid][0] = a4 * cc + om * p00;
    blL[tid][1] = a4 * (-sn) + om * p01;
    blL[tid][2] = a4 * sn + om * p10;
    blL[tid][3] = a4 * cc + om * p11;
  }
  __syncthreads();
  {
    float4 vv[4] = {v0, v1, v2, v3};
#pragma unroll
    for (int k = 0; k < 4; ++k) {
      int e0 = (k * 256 + tid) * 4;
      int row = e0 >> 6;
      int ii = row >> 1;
      int rp = (row & 1) << 1;
      int col = e0 & 63;
      float* f = (float*)&vv[k];
#pragma unroll
      for (int j = 0; j < 4; ++j) {
        int cc2 = col + j;
        if ((cc2 >> 1) == ii) f[j] = blL[ii][rp | (cc2 & 1)];
      }
      ((float4*)dst)[k * 256 + tid] = vv[k];
    }
  }
}

extern "C" void kernel_launch(void* const* d_in, const int* in_sizes, int n_in,
                              void* d_out, int out_size, void* d_ws, size_t ws_size,
                              hipStream_t stream) {
  const float* pos  = (const float*)d_in[0];
  const float* emb  = (const float*)d_in[1];
  const float* Fg   = (const float*)d_in[2];
  const float* logQ = (const float*)d_in[3];
  const float* logR = (const float*)d_in[4];
  const float* Hw   = (const float*)d_in[5];
  const float* w1   = (const float*)d_in[6];
  const float* b1   = (const float*)d_in[7];
  const float* w2   = (const float*)d_in[8];
  const float* b2   = (const float*)d_in[9];
  const float* ow   = (const float*)d_in[10];
  const float* ob   = (const float*)d_in[11];

  float* corr  = (float*)d_out;
  float* covs  = corr + 67108864;   // B*T*64*64
  float* probs = corr + 83886080;   // + B*T*32*32

  float* ws   = (float*)d_ws;
  float* zws  = ws;                    // 1048576 floats
  int*   gate = (int*)(ws + 1048576);  // 2048 ints
  float* cinv = ws + 1050624;          // 1024
  float* htr  = ws + 1051648;          // 2048
  float* su   = ws + 1053696;          // 16777216

  hipLaunchKernelGGL(k_setup, dim3(1), dim3(256), 0, stream, Hw, logR, cinv, htr);
  hipLaunchKernelGGL(k_obs, dim3(4096), dim3(256), 0, stream, emb, w1, b1, w2, b2, ow, ob, probs, zws);
  hipLaunchKernelGGL(k_gate, dim3(8), dim3(256), 0, stream, probs, gate);
  hipLaunchKernelGGL(k_scan2, dim3(8), dim3(64), 0, stream, Fg, logQ, probs, gate, cinv, covs, su);
  hipLaunchKernelGGL(k_corr, dim3(16384), dim3(256), 0, stream, pos, zws, probs, gate, Hw, htr, su, corr);
}

// Round 4
// 5501.461 us; speedup vs baseline: 3.6865x; 1.3581x over previous
//
#include <hip/hip_runtime.h>
#include <math.h>

#define TT 2048
#define NB 8

typedef __attribute__((ext_vector_type(16))) float f32x16;
typedef __attribute__((ext_vector_type(8))) __bf16 bf16x8;

// ---------- pack helpers (RNE hi; residual lo) ----------
__device__ __forceinline__ bf16x8 ph(const f32x16& x, int base) {
  bf16x8 r;
#pragma unroll
  for (int d = 0; d < 8; ++d) r[d] = (__bf16)x[base + d];
  return r;
}
__device__ __forceinline__ bf16x8 pl(const f32x16& x, int base) {
  bf16x8 r;
#pragma unroll
  for (int d = 0; d < 8; ++d) {
    float t = x[base + d];
    r[d] = (__bf16)(t - (float)((__bf16)t));
  }
  return r;
}
struct FragsH { bf16x8 h0, h1; };
struct Frags { bf16x8 h0, l0, h1, l1; };
__device__ __forceinline__ FragsH mkh(const f32x16& x) { return {ph(x, 0), ph(x, 8)}; }
__device__ __forceinline__ Frags mkf(const f32x16& x) {
  return {ph(x, 0), pl(x, 0), ph(x, 8), pl(x, 8)};
}

#define MFMA_B __builtin_amdgcn_mfma_f32_32x32x16_bf16
// 1-term product over K=32 (2 MFMA), accumulating onto C (exact f32 C pass-through)
__device__ __forceinline__ f32x16 mmA(bf16x8 a0, bf16x8 a1, bf16x8 b0, bf16x8 b1, f32x16 c) {
  c = MFMA_B(a0, b0, c, 0, 0, 0);
  c = MFMA_B(a1, b1, c, 0, 0, 0);
  return c;
}
// 3-term product (hh + hl + lh), accumulating onto C
__device__ __forceinline__ f32x16 mm6(const Frags& A, const Frags& B, f32x16 c) {
  f32x16 u = {};
  c = MFMA_B(A.h0, B.h0, c, 0, 0, 0);  u = MFMA_B(A.h0, B.l0, u, 0, 0, 0);
  c = MFMA_B(A.h1, B.h1, c, 0, 0, 0);  u = MFMA_B(A.h1, B.l1, u, 0, 0, 0);
  c = MFMA_B(A.l0, B.h0, c, 0, 0, 0);  u = MFMA_B(A.l1, B.h1, u, 0, 0, 0);
  return c + u;
}

// ---------- Phase 0: Cinv = (H^T R^-1 H)^-1 (32x32), HtRinv (32x64) ----------
__global__ __launch_bounds__(256) void k_setup(const float* __restrict__ Hw,
                                               const float* __restrict__ logR,
                                               float* __restrict__ cinv,
                                               float* __restrict__ htr) {
  __shared__ float C[32][33];
  __shared__ float rinv[64];
  int tid = threadIdx.x;
  if (tid < 64) rinv[tid] = expf(-logR[tid]);
  __syncthreads();
  int i = tid >> 3, j0 = (tid & 7) << 2;
  float a0 = 0.f, a1 = 0.f, a2 = 0.f, a3 = 0.f;
  for (int o = 0; o < 64; ++o) {
    float hio = Hw[o * 32 + i] * rinv[o];
    a0 += hio * Hw[o * 32 + j0];
    a1 += hio * Hw[o * 32 + j0 + 1];
    a2 += hio * Hw[o * 32 + j0 + 2];
    a3 += hio * Hw[o * 32 + j0 + 3];
  }
  C[i][j0] = a0; C[i][j0 + 1] = a1; C[i][j0 + 2] = a2; C[i][j0 + 3] = a3;
  for (int e = 0; e < 8; ++e) {
    int idx = tid * 8 + e;
    int ii = idx >> 6, o = idx & 63;
    htr[idx] = Hw[o * 32 + ii] * rinv[o];
  }
  __syncthreads();
  for (int k = 0; k < 32; ++k) {
    float ip = 1.0f / C[k][k];
    __syncthreads();
    if (tid < 32 && tid != k) C[k][tid] = -C[k][tid] * ip;
    __syncthreads();
    if (i != k) {
      float f = C[i][k];
      for (int q = 0; q < 4; ++q) {
        int j = j0 + q;
        if (j != k) C[i][j] += f * C[k][j];
      }
    }
    __syncthreads();
    if (tid < 32) {
      if (tid == k) C[k][k] = ip; else C[tid][k] *= ip;
    }
    __syncthreads();
  }
  cinv[i * 32 + j0]     = C[i][j0];
  cinv[i * 32 + j0 + 1] = C[i][j0 + 1];
  cinv[i * 32 + j0 + 2] = C[i][j0 + 2];
  cinv[i * 32 + j0 + 3] = C[i][j0 + 3];
}

// ---------- Phase 1: probs (B,T) and z = emb @ obs_w^T + obs_b ----------
__global__ __launch_bounds__(256) void k_obs(const float* __restrict__ emb,
                                             const float* __restrict__ w1,
                                             const float* __restrict__ b1,
                                             const float* __restrict__ w2,
                                             const float* __restrict__ b2,
                                             const float* __restrict__ ow,
                                             const float* __restrict__ ob,
                                             float* __restrict__ probs_out,
                                             float* __restrict__ zws) {
  int wave = threadIdx.x >> 6, lane = threadIdx.x & 63;
  int row = blockIdx.x * 4 + wave;
  float xv = emb[(size_t)row * 64 + lane];
  const float4* w1v = (const float4*)(w1 + lane * 64);
  float hacc = b1[lane];
#pragma unroll
  for (int i4 = 0; i4 < 16; ++i4) {
    float4 wv = w1v[i4];
    hacc += __shfl(xv, i4 * 4, 64) * wv.x + __shfl(xv, i4 * 4 + 1, 64) * wv.y +
            __shfl(xv, i4 * 4 + 2, 64) * wv.z + __shfl(xv, i4 * 4 + 3, 64) * wv.w;
  }
  float h = fmaxf(hacc, 0.f);
  float s = h * w2[lane];
#pragma unroll
  for (int off = 32; off; off >>= 1) s += __shfl_xor(s, off, 64);
  float prob = 1.0f / (1.0f + expf(-(s + b2[0])));
  if (lane == 0) probs_out[row] = prob;
  const float4* owv = (const float4*)(ow + lane * 64);
  float zacc = ob[lane];
#pragma unroll
  for (int i4 = 0; i4 < 16; ++i4) {
    float4 wv = owv[i4];
    zacc += __shfl(xv, i4 * 4, 64) * wv.x + __shfl(xv, i4 * 4 + 1, 64) * wv.y +
            __shfl(xv, i4 * 4 + 2, 64) * wv.z + __shfl(xv, i4 * 4 + 3, 64) * wv.w;
  }
  zws[(size_t)row * 64 + lane] = zacc;
}

// ---------- Phase 1b: gate[t] = any_b(probs[b][t] > 0.5) ----------
__global__ void k_gate(const float* __restrict__ probs_out, int* __restrict__ gate) {
  int t = blockIdx.x * 256 + threadIdx.x;
  if (t < TT) {
    int g = 0;
    for (int b = 0; b < NB; ++b) g |= (probs_out[b * TT + t] > 0.5f) ? 1 : 0;
    gate[t] = g;
  }
}

// ---------- Phase 2: Riccati scan — one wave/batch, power-sum Newton --------
// C/D layout: lane l=(c=l&31, hh=l>>5), reg q -> (row rq, col c),
// rq=(q&3)+8*(q>>2)+4*hh.
// Roles (validated R2/R3): resident-as-argA => Z^T ; resident-as-argB => Z ;
// const pattern V[c*32+colmap] as argA => V ; as argB => V^T.
__global__ __launch_bounds__(64, 1) void k_scan2(const float* __restrict__ Fg,
                                                 const float* __restrict__ logQ,
                                                 const float* __restrict__ probs_out,
                                                 const int* __restrict__ gate,
                                                 const float* __restrict__ cinv,
                                                 float* __restrict__ covs,
                                                 float* __restrict__ su_ws) {
  __shared__ float probL[TT];
  __shared__ int gateL[TT];
  const int b = blockIdx.x, l = threadIdx.x;
  const int hh = l >> 5, c = l & 31;

  for (int i = l; i < TT / 4; i += 64) {
    ((float4*)probL)[i] = ((const float4*)(probs_out + (size_t)b * TT))[i];
    ((int4*)gateL)[i] = ((const int4*)gate)[i];
  }

  // Constants: A = F - I (2-term), Cinv (3-term), exact identity
  f32x16 vA, vC, vI;
#pragma unroll
  for (int s = 0; s < 2; ++s)
#pragma unroll
    for (int i = 0; i < 8; ++i) {
      int col = 16 * s + 4 * hh + (i & 3) + 8 * (i >> 2);
      int q = i + 8 * s;
      vA[q] = Fg[c * 32 + col] - ((col == c) ? 1.0f : 0.0f);
      vC[q] = cinv[c * 32 + col];
      vI[q] = (col == c) ? 1.0f : 0.0f;
    }
  const FragsH aFh = mkh(vA);
  const FragsH aFl = {pl(vA, 0), pl(vA, 8)};
  const Frags Cf = mkf(vC);
  const FragsH Id = mkh(vI);

  f32x16 qdv, sig, Xv;
  float qc = expf(logQ[c]);
#pragma unroll
  for (int q = 0; q < 16; ++q) {
    int rq = (q & 3) + 8 * (q >> 2) + 4 * hh;
    qdv[q] = (rq == c) ? qc : 0.0f;
    sig[q] = (rq == c) ? 0.01f : 0.0f;
    Xv[q] = 0.0f;  // forces Jordan on first gated step
  }

  float* cb = covs + (((size_t)b * TT) << 10) + c;
  float* sb = su_ws + (((size_t)b * TT) << 10) + c;
  __syncthreads();
  float a3 = probL[0];
  int g = gateL[0];

#pragma unroll 1
  for (int t = 0; t < TT; ++t) {
    float a3n = probL[(t + 1) & (TT - 1)];
    int gn = gateL[(t + 1) & (TT - 1)];

    // G2 = Sigma + Sigma*A^T ; P = G2 + A*G2 + diag(Qd)   (F = I + A exactly)
    FragsH Sh = mkh(sig);
    f32x16 g2 = mmA(Sh.h0, Sh.h1, aFl.h0, aFl.h1,
                    mmA(Sh.h0, Sh.h1, aFh.h0, aFh.h1, sig));
    FragsH G2h = mkh(g2);
    f32x16 p = mmA(aFl.h0, aFl.h1, G2h.h0, G2h.h1,
                   mmA(aFh.h0, aFh.h1, G2h.h0, G2h.h1, g2 + qdv));

    if (g) {
      const f32x16 zz = {};
      Frags Pf = mkf(p);
      FragsH Xh = mkh(Xv);
      // T0 = M*X = P*X + Cinv*X  (1-term check)
      f32x16 T0 = mmA(Pf.h0, Pf.h1, Xh.h0, Xh.h1,
                      mmA(Cf.h0, Cf.h1, Xh.h0, Xh.h1, zz));
      float csum = 0.f;
#pragma unroll
      for (int q = 0; q < 16; ++q) {
        int rq = (q & 3) + 8 * (q >> 2) + 4 * hh;
        csum += fabsf(((rq == c) ? 1.0f : 0.0f) - T0[q]);
      }
      csum += __shfl_xor(csum, 32);  // full |col sum| of E0 = I - M X

      if (__all(csum < 0.62f)) {
        // power-sum block: X2 = X (I + E + E^2 + E^3), E = I - T0  (E -> E^4)
        f32x16 E;
#pragma unroll
        for (int q = 0; q < 16; ++q) {
          int rq = (q & 3) + 8 * (q >> 2) + 4 * hh;
          E[q] = ((rq == c) ? 1.0f : 0.0f) - T0[q];
        }
        FragsH Eh = mkh(E);
        f32x16 S1 = mmA(Xh.h0, Xh.h1, Eh.h0, Eh.h1, zz);
        FragsH S1h = mkh(S1);
        f32x16 S2 = mmA(S1h.h0, S1h.h1, Eh.h0, Eh.h1, zz);
        FragsH S2h = mkh(S2);
        f32x16 S3 = mmA(S2h.h0, S2h.h1, Eh.h0, Eh.h1, zz);
        f32x16 X2 = Xv + S1 + S2 + S3;
        if (!__all(csum < 0.40f)) {
          // second block for 0.40 <= csum < 0.62
          FragsH X2h = mkh(X2);
          f32x16 T1 = mmA(Pf.h0, Pf.h1, X2h.h0, X2h.h1,
                          mmA(Cf.h0, Cf.h1, X2h.h0, X2h.h1, zz));
          f32x16 E1;
#pragma unroll
          for (int q = 0; q < 16; ++q) {
            int rq = (q & 3) + 8 * (q >> 2) + 4 * hh;
            E1[q] = ((rq == c) ? 1.0f : 0.0f) - T1[q];
          }
          FragsH E1h = mkh(E1);
          f32x16 U1 = mmA(X2h.h0, X2h.h1, E1h.h0, E1h.h1, zz);
          FragsH U1h = mkh(U1);
          f32x16 U2 = mmA(U1h.h0, U1h.h1, E1h.h0, E1h.h1, zz);
          FragsH U2h = mkh(U2);
          f32x16 U3 = mmA(U2h.h0, U2h.h1, E1h.h0, E1h.h1, zz);
          X2 = X2 + U1 + U2 + U3;
        }
        // symmetrize (1-term transpose via identity), then exact final stage
        FragsH Xq = mkh(X2);
        f32x16 Xt = mmA(Xq.h0, Xq.h1, Id.h0, Id.h1, zz);
        f32x16 Xs = 0.5f * (X2 + Xt);
        Frags Xfs = mkf(Xs);
        f32x16 T3 = mm6(Pf, Xfs, mm6(Cf, Xfs, zz));  // 3-term M*Xs
        f32x16 E3;
#pragma unroll
        for (int q = 0; q < 16; ++q) {
          int rq = (q & 3) + 8 * (q >> 2) + 4 * hh;
          E3[q] = ((rq == c) ? 1.0f : 0.0f) - T3[q];
        }
        FragsH E3h = mkh(E3);
        Xv = mmA(Xfs.h0, Xfs.h1, E3h.h0, E3h.h1, Xs);  // X4 = Xs + Xs*E3
      } else {
        // ---- Jordan-exchange fallback (validated path, rare) ----
        float m[16];
#pragma unroll
        for (int q = 0; q < 16; ++q) {
          int rq = (q & 3) + 8 * (q >> 2) + 4 * hh;
          m[q] = p[q] + cinv[rq * 32 + c];
        }
#pragma unroll
        for (int k = 0; k < 32; ++k) {
          const int hk = (k >> 2) & 1;
          const int qk = (k & 3) | ((k >> 3) << 2);
          float pv = __shfl(m[qk], k + 32 * hk, 64);
          float r0 = __builtin_amdgcn_rcpf(pv);
          float ip = r0 * (2.0f - pv * r0);
          const bool myrow = (c == k);
#pragma unroll
          for (int q = 0; q < 16; ++q) {
            bool isdiag = (q == qk) && (hh == hk);
            float sc = -m[q] * ip;
            m[q] = (myrow && !isdiag) ? sc : m[q];
          }
          float fk = __shfl(m[qk], c + 32 * hk, 64);
          float prv[16];
#pragma unroll
          for (int q = 0; q < 16; ++q) prv[q] = __shfl(m[q], k + 32 * hh, 64);
#pragma unroll
          for (int q = 0; q < 16; ++q) {
            bool pivcol = (q == qk) && (hh == hk);
            float upd = fmaf(fk, prv[q], m[q]);
            m[q] = (!myrow && !pivcol) ? upd : m[q];
          }
          float cf = myrow ? ip : fk * ip;
          m[qk] = (hh == hk) ? cf : m[qk];
        }
#pragma unroll
        for (int q = 0; q < 16; ++q) Xv[q] = m[q];
      }

      // Y = W*P ; Su = Cinv*Y   (3-term)
      const f32x16 zz2 = {};
      Frags Wf = mkf(Xv);
      f32x16 Y = mm6(Wf, Pf, zz2);
      Frags Yf = mkf(Y);
      f32x16 Su = mm6(Cf, Yf, zz2);

      const float om = 1.0f - a3;
#pragma unroll
      for (int q = 0; q < 16; ++q) {
        int rq = (q & 3) + 8 * (q >> 2) + 4 * hh;
        float sg = a3 * Su[q] + om * p[q];
        sig[q] = sg;
        cb[rq * 32] = sg;
        sb[rq * 32] = Su[q];
      }
    } else {
      sig = p;
#pragma unroll
      for (int q = 0; q < 16; ++q) {
        int rq = (q & 3) + 8 * (q >> 2) + 4 * hh;
        cb[rq * 32] = p[q];
      }
    }
    cb += 1024;
    sb += 1024;
    a3 = a3n;
    g = gn;
  }
}

// ---------- Phase 3: fused positions->corr copy + diag-block blend ----------
__global__ __launch_bounds__(256) void k_corr(const float* __restrict__ pos,
                                              const float* __restrict__ zws,
                                              const float* __restrict__ probs_out,
                                              const int* __restrict__ gate,
                                              const float* __restrict__ Hw,
                                              const float* __restrict__ htr,
                                              const float* __restrict__ su_ws,
                                              float* __restrict__ corr) {
  const int bid = blockIdx.x;
  const int b = bid >> 11, t = bid & 2047;
  const size_t pbase = ((size_t)bid) << 12;
  const float* src = pos + pbase;
  float* dst = corr + pbase;
  const int tid = threadIdx.x;
  const int g = gate[t];
  float4 v0 = ((const float4*)src)[tid];
  float4 v1 = ((const float4*)src)[256 + tid];
  float4 v2 = ((const float4*)src)[512 + tid];
  float4 v3 = ((const float4*)src)[768 + tid];
  if (!g) {
    ((float4*)dst)[tid] = v0;
    ((float4*)dst)[256 + tid] = v1;
    ((float4*)dst)[512 + tid] = v2;
    ((float4*)dst)[768 + tid] = v3;
    return;
  }
  __shared__ float muL[32], yL[64], vL[32], blL[32][4];
  float a4 = probs_out[b * TT + t];
  float p00 = 0.f, p01 = 0.f, p10 = 0.f, p11 = 0.f, mu = 0.f;
  if (tid < 32) {
    int ii = tid;
    p00 = src[(2 * ii) * 64 + 2 * ii];
    p01 = src[(2 * ii) * 64 + 2 * ii + 1];
    p10 = src[(2 * ii + 1) * 64 + 2 * ii];
    p11 = src[(2 * ii + 1) * 64 + 2 * ii + 1];
    mu = atan2f(p10, p00);
    muL[ii] = mu;
  }
  __syncthreads();
  if (tid < 64) {
    int o = tid;
    float zo = zws[((size_t)bid) * 64 + o];
    const float4* hrow = (const float4*)(Hw + o * 32);
    float s = 0.f;
#pragma unroll
    for (int i4 = 0; i4 < 8; ++i4) {
      float4 hv = hrow[i4];
      s += muL[i4 * 4] * hv.x + muL[i4 * 4 + 1] * hv.y +
           muL[i4 * 4 + 2] * hv.z + muL[i4 * 4 + 3] * hv.w;
    }
    yL[o] = zo - s;
  }
  __syncthreads();
  if (tid < 32) {
    const float4* hr = (const float4*)(htr + tid * 64);
    float s = 0.f;
#pragma unroll
    for (int j4 = 0; j4 < 16; ++j4) {
      float4 hv = hr[j4];
      s += yL[j4 * 4] * hv.x + yL[j4 * 4 + 1] * hv.y +
           yL[j4 * 4 + 2] * hv.z + yL[j4 * 4 + 3] * hv.w;
    }
    vL[tid] = s;
  }
  __syncthreads();
  if (tid < 32) {
    const float4* srow = (const float4*)(su_ws + (((size_t)bid) << 10) + tid * 32);
    float s = 0.f;
#pragma unroll
    for (int j4 = 0; j4 < 8; ++j4) {
      float4 sv = srow[j4];
      s += vL[j4 * 4] * sv.x + vL[j4 * 4 + 1] * sv.y +
           vL[j4 * 4 + 2] * sv.z + vL[j4 * 4 + 3] * sv.w;
    }
    float mc = mu + s;
    float cc = cosf(mc), sn = sinf(mc);
    float om = 1.0f - a4;
    blL[tid][0] = a4 * cc + om * p00;
    blL[tid][1] = a4 * (-sn) + om * p01;
    blL[tid][2] = a4 * sn + om * p10;
    blL[tid][3] = a4 * cc + om * p11;
  }
  __syncthreads();
  {
    float4 vv[4] = {v0, v1, v2, v3};
#pragma unroll
    for (int k = 0; k < 4; ++k) {
      int e0 = (k * 256 + tid) * 4;
      int row = e0 >> 6;
      int ii = row >> 1;
      int rp = (row & 1) << 1;
      int col = e0 & 63;
      float* f = (float*)&vv[k];
#pragma unroll
      for (int j = 0; j < 4; ++j) {
        int cc2 = col + j;
        if ((cc2 >> 1) == ii) f[j] = blL[ii][rp | (cc2 & 1)];
      }
      ((float4*)dst)[k * 256 + tid] = vv[k];
    }
  }
}

extern "C" void kernel_launch(void* const* d_in, const int* in_sizes, int n_in,
                              void* d_out, int out_size, void* d_ws, size_t ws_size,
                              hipStream_t stream) {
  const float* pos  = (const float*)d_in[0];
  const float* emb  = (const float*)d_in[1];
  const float* Fg   = (const float*)d_in[2];
  const float* logQ = (const float*)d_in[3];
  const float* logR = (const float*)d_in[4];
  const float* Hw   = (const float*)d_in[5];
  const float* w1   = (const float*)d_in[6];
  const float* b1   = (const float*)d_in[7];
  const float* w2   = (const float*)d_in[8];
  const float* b2   = (const float*)d_in[9];
  const float* ow   = (const float*)d_in[10];
  const float* ob   = (const float*)d_in[11];

  float* corr  = (float*)d_out;
  float* covs  = corr + 67108864;   // B*T*64*64
  float* probs = corr + 83886080;   // + B*T*32*32

  float* ws   = (float*)d_ws;
  float* zws  = ws;                    // 1048576 floats
  int*   gate = (int*)(ws + 1048576);  // 2048 ints
  float* cinv = ws + 1050624;          // 1024
  float* htr  = ws + 1051648;          // 2048
  float* su   = ws + 1053696;          // 16777216

  hipLaunchKernelGGL(k_setup, dim3(1), dim3(256), 0, stream, Hw, logR, cinv, htr);
  hipLaunchKernelGGL(k_obs, dim3(4096), dim3(256), 0, stream, emb, w1, b1, w2, b2, ow, ob, probs, zws);
  hipLaunchKernelGGL(k_gate, dim3(8), dim3(256), 0, stream, probs, gate);
  hipLaunchKernelGGL(k_scan2, dim3(8), dim3(64), 0, stream, Fg, logQ, probs, gate, cinv, covs, su);
  hipLaunchKernelGGL(k_corr, dim3(16384), dim3(256), 0, stream, pos, zws, probs, gate, Hw, htr, su, corr);
}

// Round 6
// 5488.730 us; speedup vs baseline: 3.6950x; 1.0023x over previous
//
#include <hip/hip_runtime.h>
#include <math.h>

#define TT 2048
#define NB 8

typedef __attribute__((ext_vector_type(16))) float f32x16;
typedef __attribute__((ext_vector_type(8))) __bf16 bf16x8;

// ---------- pack helpers (RNE hi; residual lo) ----------
__device__ __forceinline__ bf16x8 ph(const f32x16& x, int base) {
  bf16x8 r;
#pragma unroll
  for (int d = 0; d < 8; ++d) r[d] = (__bf16)x[base + d];
  return r;
}
__device__ __forceinline__ bf16x8 pl(const f32x16& x, int base) {
  bf16x8 r;
#pragma unroll
  for (int d = 0; d < 8; ++d) {
    float t = x[base + d];
    r[d] = (__bf16)(t - (float)((__bf16)t));
  }
  return r;
}
struct FragsH { bf16x8 h0, h1; };
struct Frags { bf16x8 h0, l0, h1, l1; };
__device__ __forceinline__ FragsH mkh(const f32x16& x) { return {ph(x, 0), ph(x, 8)}; }
__device__ __forceinline__ Frags mkf(const f32x16& x) {
  return {ph(x, 0), pl(x, 0), ph(x, 8), pl(x, 8)};
}

#define MFMA_B __builtin_amdgcn_mfma_f32_32x32x16_bf16
// 1-term product over K=32 (2 MFMA), accumulating onto C (exact f32 C pass-through)
__device__ __forceinline__ f32x16 mmA(bf16x8 a0, bf16x8 a1, bf16x8 b0, bf16x8 b1, f32x16 c) {
  c = MFMA_B(a0, b0, c, 0, 0, 0);
  c = MFMA_B(a1, b1, c, 0, 0, 0);
  return c;
}
// 3-term product (hh + hl + lh), accumulating onto C
__device__ __forceinline__ f32x16 mm6(const Frags& A, const Frags& B, f32x16 c) {
  f32x16 u = {};
  c = MFMA_B(A.h0, B.h0, c, 0, 0, 0);  u = MFMA_B(A.h0, B.l0, u, 0, 0, 0);
  c = MFMA_B(A.h1, B.h1, c, 0, 0, 0);  u = MFMA_B(A.h1, B.l1, u, 0, 0, 0);
  c = MFMA_B(A.l0, B.h0, c, 0, 0, 0);  u = MFMA_B(A.l1, B.h1, u, 0, 0, 0);
  return c + u;
}

// ---------- Phase 0: Cinv = (H^T R^-1 H)^-1 (32x32), HtRinv (32x64) ----------
__global__ __launch_bounds__(256) void k_setup(const float* __restrict__ Hw,
                                               const float* __restrict__ logR,
                                               float* __restrict__ cinv,
                                               float* __restrict__ htr) {
  __shared__ float C[32][33];
  __shared__ float rinv[64];
  int tid = threadIdx.x;
  if (tid < 64) rinv[tid] = expf(-logR[tid]);
  __syncthreads();
  int i = tid >> 3, j0 = (tid & 7) << 2;
  float a0 = 0.f, a1 = 0.f, a2 = 0.f, a3 = 0.f;
  for (int o = 0; o < 64; ++o) {
    float hio = Hw[o * 32 + i] * rinv[o];
    a0 += hio * Hw[o * 32 + j0];
    a1 += hio * Hw[o * 32 + j0 + 1];
    a2 += hio * Hw[o * 32 + j0 + 2];
    a3 += hio * Hw[o * 32 + j0 + 3];
  }
  C[i][j0] = a0; C[i][j0 + 1] = a1; C[i][j0 + 2] = a2; C[i][j0 + 3] = a3;
  for (int e = 0; e < 8; ++e) {
    int idx = tid * 8 + e;
    int ii = idx >> 6, o = idx & 63;
    htr[idx] = Hw[o * 32 + ii] * rinv[o];
  }
  __syncthreads();
  for (int k = 0; k < 32; ++k) {
    float ip = 1.0f / C[k][k];
    __syncthreads();
    if (tid < 32 && tid != k) C[k][tid] = -C[k][tid] * ip;
    __syncthreads();
    if (i != k) {
      float f = C[i][k];
      for (int q = 0; q < 4; ++q) {
        int j = j0 + q;
        if (j != k) C[i][j] += f * C[k][j];
      }
    }
    __syncthreads();
    if (tid < 32) {
      if (tid == k) C[k][k] = ip; else C[tid][k] *= ip;
    }
    __syncthreads();
  }
  cinv[i * 32 + j0]     = C[i][j0];
  cinv[i * 32 + j0 + 1] = C[i][j0 + 1];
  cinv[i * 32 + j0 + 2] = C[i][j0 + 2];
  cinv[i * 32 + j0 + 3] = C[i][j0 + 3];
}

// ---------- Phase 1: probs (B,T) and z = emb @ obs_w^T + obs_b ----------
__global__ __launch_bounds__(256) void k_obs(const float* __restrict__ emb,
                                             const float* __restrict__ w1,
                                             const float* __restrict__ b1,
                                             const float* __restrict__ w2,
                                             const float* __restrict__ b2,
                                             const float* __restrict__ ow,
                                             const float* __restrict__ ob,
                                             float* __restrict__ probs_out,
                                             float* __restrict__ zws) {
  int wave = threadIdx.x >> 6, lane = threadIdx.x & 63;
  int row = blockIdx.x * 4 + wave;
  float xv = emb[(size_t)row * 64 + lane];
  const float4* w1v = (const float4*)(w1 + lane * 64);
  float hacc = b1[lane];
#pragma unroll
  for (int i4 = 0; i4 < 16; ++i4) {
    float4 wv = w1v[i4];
    hacc += __shfl(xv, i4 * 4, 64) * wv.x + __shfl(xv, i4 * 4 + 1, 64) * wv.y +
            __shfl(xv, i4 * 4 + 2, 64) * wv.z + __shfl(xv, i4 * 4 + 3, 64) * wv.w;
  }
  float h = fmaxf(hacc, 0.f);
  float s = h * w2[lane];
#pragma unroll
  for (int off = 32; off; off >>= 1) s += __shfl_xor(s, off, 64);
  float prob = 1.0f / (1.0f + expf(-(s + b2[0])));
  if (lane == 0) probs_out[row] = prob;
  const float4* owv = (const float4*)(ow + lane * 64);
  float zacc = ob[lane];
#pragma unroll
  for (int i4 = 0; i4 < 16; ++i4) {
    float4 wv = owv[i4];
    zacc += __shfl(xv, i4 * 4, 64) * wv.x + __shfl(xv, i4 * 4 + 1, 64) * wv.y +
            __shfl(xv, i4 * 4 + 2, 64) * wv.z + __shfl(xv, i4 * 4 + 3, 64) * wv.w;
  }
  zws[(size_t)row * 64 + lane] = zacc;
}

// ---------- Phase 1b: gate[t] = any_b(probs[b][t] > 0.5) ----------
__global__ void k_gate(const float* __restrict__ probs_out, int* __restrict__ gate) {
  int t = blockIdx.x * 256 + threadIdx.x;
  if (t < TT) {
    int g = 0;
    for (int b = 0; b < NB; ++b) g |= (probs_out[b * TT + t] > 0.5f) ? 1 : 0;
    gate[t] = g;
  }
}

// ---------- Phase 2: Riccati scan — one wave/batch, NS + symmetrize + exact --
// C/D layout: lane l=(c=l&31, hh=l>>5), reg q -> (row rq, col c),
// rq=(q&3)+8*(q>>2)+4*hh.
// Roles (validated R2-R4): resident-as-argA => Z^T ; resident-as-argB => Z ;
// const pattern V[c*32+colmap] as argA => V ; as argB => V^T.
// NS X<-2X-X^T(MX) DOUBLES antisym(X) per step (the 2X term) -> must
// re-symmetrize each time-step; exact 3-term final stage vs full M kills the
// hi(M)-bias (both were R4-proven; dropping them broke R5).
// Su = Cinv - Cinv*X*Cinv (exact identity: W*P = I - W*Cinv).
__global__ __launch_bounds__(64, 1) void k_scan2(const float* __restrict__ Fg,
                                                 const float* __restrict__ logQ,
                                                 const float* __restrict__ probs_out,
                                                 const int* __restrict__ gate,
                                                 const float* __restrict__ cinv,
                                                 float* __restrict__ covs,
                                                 float* __restrict__ su_ws) {
  __shared__ float probL[TT];
  __shared__ int gateL[TT];
  const int b = blockIdx.x, l = threadIdx.x;
  const int hh = l >> 5, c = l & 31;

  for (int i = l; i < TT / 4; i += 64) {
    ((float4*)probL)[i] = ((const float4*)(probs_out + (size_t)b * TT))[i];
    ((int4*)gateL)[i] = ((const int4*)gate)[i];
  }

  // Constants (B-map pattern): A = F - I (2-term), Cinv (3-term), identity
  f32x16 vA, vC, vI;
#pragma unroll
  for (int s = 0; s < 2; ++s)
#pragma unroll
    for (int i = 0; i < 8; ++i) {
      int col = 16 * s + 4 * hh + (i & 3) + 8 * (i >> 2);
      int q = i + 8 * s;
      vA[q] = Fg[c * 32 + col] - ((col == c) ? 1.0f : 0.0f);
      vC[q] = cinv[c * 32 + col];
      vI[q] = (col == c) ? 1.0f : 0.0f;
    }
  const FragsH aFh = mkh(vA);
  const FragsH aFl = {pl(vA, 0), pl(vA, 8)};
  const Frags Cf = mkf(vC);
  const FragsH Idh = mkh(vI);

  // D-map constants
  f32x16 dq, qdv, ciD, sig, Xv;
  float qc = expf(logQ[c]);
#pragma unroll
  for (int q = 0; q < 16; ++q) {
    int rq = (q & 3) + 8 * (q >> 2) + 4 * hh;
    dq[q] = (rq == c) ? 1.0f : 0.0f;
    qdv[q] = (rq == c) ? qc : 0.0f;
    ciD[q] = cinv[rq * 32 + c];
    sig[q] = (rq == c) ? 0.01f : 0.0f;
    Xv[q] = 0.0f;  // forces Jordan on first gated step
  }
  bf16x8 Xh0 = ph(Xv, 0), Xh1 = ph(Xv, 8);

  float* cbase = covs + (((size_t)b * TT) << 10) + c * 32 + 4 * hh;
  float* sbase = su_ws + (((size_t)b * TT) << 10) + c * 32 + 4 * hh;
  __syncthreads();
  float a3 = probL[0];
  int g = gateL[0];

#pragma unroll 1
  for (int t = 0; t < TT; ++t) {
    float a3n = probL[(t + 1) & (TT - 1)];
    int gn = gateL[(t + 1) & (TT - 1)];

    // G2 = Sigma + Sigma*A^T ; P = G2 + A*G2 + diag(Qd)   (F = I + A; A 2-term)
    FragsH Sh = mkh(sig);
    f32x16 g2 = mmA(Sh.h0, Sh.h1, aFl.h0, aFl.h1,
                    mmA(Sh.h0, Sh.h1, aFh.h0, aFh.h1, sig));
    FragsH G2h = mkh(g2);
    f32x16 p = mmA(aFl.h0, aFl.h1, G2h.h0, G2h.h1,
                   mmA(aFh.h0, aFh.h1, G2h.h0, G2h.h1, g2 + qdv));

    if (g) {
      const f32x16 zz = {};
      f32x16 M = p + ciD;
      Frags Mf = mkf(M);  // hi for NS probes; full for exact final stage
      // T = M*X (warm-start residual probe; reused as NS step 1's MX)
      f32x16 T = mmA(Mf.h0, Mf.h1, Xh0, Xh1, zz);
      float csum = 0.f;
#pragma unroll
      for (int q = 0; q < 16; ++q) csum += fabsf(dq[q] - T[q]);
      csum += __shfl_xor(csum, 32);  // full |col sum| of E0 = I - M X

      if (__all(csum < 0.55f)) {
        // NS step 1: X <- 2X - X*T
        FragsH Th = mkh(T);
        f32x16 U = mmA(Xh0, Xh1, Th.h0, Th.h1, zz);
        Xv = 2.0f * Xv - U;
        // NS step 2
        FragsH Xn = mkh(Xv);
        f32x16 T2 = mmA(Mf.h0, Mf.h1, Xn.h0, Xn.h1, zz);
        FragsH T2h = mkh(T2);
        f32x16 U2 = mmA(Xn.h0, Xn.h1, T2h.h0, T2h.h1, zz);
        Xv = 2.0f * Xv - U2;
        FragsH Xp;
        if (!__all(csum < 0.30f)) {
          // NS step 3 (only for 0.30 <= csum < 0.55)
          FragsH Xn3 = mkh(Xv);
          f32x16 T3n = mmA(Mf.h0, Mf.h1, Xn3.h0, Xn3.h1, zz);
          FragsH T3h = mkh(T3n);
          f32x16 U3 = mmA(Xn3.h0, Xn3.h1, T3h.h0, T3h.h1, zz);
          Xv = 2.0f * Xv - U3;
        }
        // symmetrize: Xt = hi(X)^T exactly (bf16*1.0 products are exact)
        Xp = mkh(Xv);
        f32x16 Xt = mmA(Xp.h0, Xp.h1, Idh.h0, Idh.h1, zz);
        f32x16 Xs = 0.5f * (Xv + Xt);
        // exact Newton stage vs FULL M: X = Xs + Xs*(I - M*Xs)
        Frags Xsf = mkf(Xs);
        f32x16 T3 = mm6(Mf, Xsf, zz);
        f32x16 E3 = dq - T3;
        FragsH E3h = mkh(E3);
        Xv = mmA(Xsf.h0, Xsf.h1, E3h.h0, E3h.h1, Xs);
      } else {
        // ---- Jordan-exchange fallback (validated path, rare) ----
        float m[16];
#pragma unroll
        for (int q = 0; q < 16; ++q) m[q] = M[q];
#pragma unroll
        for (int k = 0; k < 32; ++k) {
          const int hk = (k >> 2) & 1;
          const int qk = (k & 3) | ((k >> 3) << 2);
          float pv = __shfl(m[qk], k + 32 * hk, 64);
          float r0 = __builtin_amdgcn_rcpf(pv);
          float ip = r0 * (2.0f - pv * r0);
          const bool myrow = (c == k);
#pragma unroll
          for (int q = 0; q < 16; ++q) {
            bool isdiag = (q == qk) && (hh == hk);
            float sc = -m[q] * ip;
            m[q] = (myrow && !isdiag) ? sc : m[q];
          }
          float fk = __shfl(m[qk], c + 32 * hk, 64);
          float prv[16];
#pragma unroll
          for (int q = 0; q < 16; ++q) prv[q] = __shfl(m[q], k + 32 * hh, 64);
#pragma unroll
          for (int q = 0; q < 16; ++q) {
            bool pivcol = (q == qk) && (hh == hk);
            float upd = fmaf(fk, prv[q], m[q]);
            m[q] = (!myrow && !pivcol) ? upd : m[q];
          }
          float cf = myrow ? ip : fk * ip;
          m[qk] = (hh == hk) ? cf : m[qk];
        }
#pragma unroll
        for (int q = 0; q < 16; ++q) Xv[q] = m[q];
      }

      const f32x16 zz2 = {};
      // persistent warm-start pack (hi reused for the 3-term Xf below)
      Xh0 = ph(Xv, 0);
      Xh1 = ph(Xv, 8);
      Frags Xf = {Xh0, pl(Xv, 0), Xh1, pl(Xv, 8)};
      // Su = Cinv * (I - X*Cinv)   (exact identity)
      f32x16 t5 = mm6(Xf, Cf, zz2);     // X*Cinv
      f32x16 Y = dq - t5;
      Frags Yf = mkf(Y);
      f32x16 Su = mm6(Cf, Yf, zz2);     // Cinv*Y

      const float om = 1.0f - a3;
      f32x16 sg = a3 * Su + om * p;
      sig = sg;
      // transposed float4 stores (all matrices symmetric): covs[c][rq]
#pragma unroll
      for (int j4 = 0; j4 < 4; ++j4) {
        float4 v;
        v.x = sg[4 * j4]; v.y = sg[4 * j4 + 1];
        v.z = sg[4 * j4 + 2]; v.w = sg[4 * j4 + 3];
        *(float4*)(cbase + 8 * j4) = v;
        float4 w;
        w.x = Su[4 * j4]; w.y = Su[4 * j4 + 1];
        w.z = Su[4 * j4 + 2]; w.w = Su[4 * j4 + 3];
        *(float4*)(sbase + 8 * j4) = w;
      }
    } else {
      sig = p;
#pragma unroll
      for (int j4 = 0; j4 < 4; ++j4) {
        float4 v;
        v.x = p[4 * j4]; v.y = p[4 * j4 + 1];
        v.z = p[4 * j4 + 2]; v.w = p[4 * j4 + 3];
        *(float4*)(cbase + 8 * j4) = v;
      }
    }
    cbase += 1024;
    sbase += 1024;
    a3 = a3n;
    g = gn;
  }
}

// ---------- Phase 3: fused positions->corr copy + diag-block blend ----------
__global__ __launch_bounds__(256) void k_corr(const float* __restrict__ pos,
                                              const float* __restrict__ zws,
                                              const float* __restrict__ probs_out,
                                              const int* __restrict__ gate,
                                              const float* __restrict__ Hw,
                                              const float* __restrict__ htr,
                                              const float* __restrict__ su_ws,
                                              float* __restrict__ corr) {
  const int bid = blockIdx.x;
  const int b = bid >> 11, t = bid & 2047;
  const size_t pbase = ((size_t)bid) << 12;
  const float* src = pos + pbase;
  float* dst = corr + pbase;
  const int tid = threadIdx.x;
  const int g = gate[t];
  float4 v0 = ((const float4*)src)[tid];
  float4 v1 = ((const float4*)src)[256 + tid];
  float4 v2 = ((const float4*)src)[512 + tid];
  float4 v3 = ((const float4*)src)[768 + tid];
  if (!g) {
    ((float4*)dst)[tid] = v0;
    ((float4*)dst)[256 + tid] = v1;
    ((float4*)dst)[512 + tid] = v2;
    ((float4*)dst)[768 + tid] = v3;
    return;
  }
  __shared__ float muL[32], yL[64], vL[32], blL[32][4];
  float a4 = probs_out[b * TT + t];
  float p00 = 0.f, p01 = 0.f, p10 = 0.f, p11 = 0.f, mu = 0.f;
  if (tid < 32) {
    int ii = tid;
    p00 = src[(2 * ii) * 64 + 2 * ii];
    p01 = src[(2 * ii) * 64 + 2 * ii + 1];
    p10 = src[(2 * ii + 1) * 64 + 2 * ii];
    p11 = src[(2 * ii + 1) * 64 + 2 * ii + 1];
    mu = atan2f(p10, p00);
    muL[ii] = mu;
  }
  __syncthreads();
  if (tid < 64) {
    int o = tid;
    float zo = zws[((size_t)bid) * 64 + o];
    const float4* hrow = (const float4*)(Hw + o * 32);
    float s = 0.f;
#pragma unroll
    for (int i4 = 0; i4 < 8; ++i4) {
      float4 hv = hrow[i4];
      s += muL[i4 * 4] * hv.x + muL[i4 * 4 + 1] * hv.y +
           muL[i4 * 4 + 2] * hv.z + muL[i4 * 4 + 3] * hv.w;
    }
    yL[o] = zo - s;
  }
  __syncthreads();
  if (tid < 32) {
    const float4* hr = (const float4*)(htr + tid * 64);
    float s = 0.f;
#pragma unroll
    for (int j4 = 0; j4 < 16; ++j4) {
      float4 hv = hr[j4];
      s += yL[j4 * 4] * hv.x + yL[j4 * 4 + 1] * hv.y +
           yL[j4 * 4 + 2] * hv.z + yL[j4 * 4 + 3] * hv.w;
    }
    vL[tid] = s;
  }
  __syncthreads();
  if (tid < 32) {
    const float4* srow = (const float4*)(su_ws + (((size_t)bid) << 10) + tid * 32);
    float s = 0.f;
#pragma unroll
    for (int j4 = 0; j4 < 8; ++j4) {
      float4 sv = srow[j4];
      s += vL[j4 * 4] * sv.x + vL[j4 * 4 + 1] * sv.y +
           vL[j4 * 4 + 2] * sv.z + vL[j4 * 4 + 3] * sv.w;
    }
    float mc = mu + s;
    float cc = cosf(mc), sn = sinf(mc);
    float om = 1.0f - a4;
    blL[tid][0] = a4 * cc + om * p00;
    blL[tid][1] = a4 * (-sn) + om * p01;
    blL[tid][2] = a4 * sn + om * p10;
    blL[tid][3] = a4 * cc + om * p11;
  }
  __syncthreads();
  {
    float4 vv[4] = {v0, v1, v2, v3};
#pragma unroll
    for (int k = 0; k < 4; ++k) {
      int e0 = (k * 256 + tid) * 4;
      int row = e0 >> 6;
      int ii = row >> 1;
      int rp = (row & 1) << 1;
      int col = e0 & 63;
      float* f = (float*)&vv[k];
#pragma unroll
      for (int j = 0; j < 4; ++j) {
        int cc2 = col + j;
        if ((cc2 >> 1) == ii) f[j] = blL[ii][rp | (cc2 & 1)];
      }
      ((float4*)dst)[k * 256 + tid] = vv[k];
    }
  }
}

extern "C" void kernel_launch(void* const* d_in, const int* in_sizes, int n_in,
                              void* d_out, int out_size, void* d_ws, size_t ws_size,
                              hipStream_t stream) {
  const float* pos  = (const float*)d_in[0];
  const float* emb  = (const float*)d_in[1];
  const float* Fg   = (const float*)d_in[2];
  const float* logQ = (const float*)d_in[3];
  const float* logR = (const float*)d_in[4];
  const float* Hw   = (const float*)d_in[5];
  const float* w1   = (const float*)d_in[6];
  const float* b1   = (const float*)d_in[7];
  const float* w2   = (const float*)d_in[8];
  const float* b2   = (const float*)d_in[9];
  const float* ow   = (const float*)d_in[10];
  const float* ob   = (const float*)d_in[11];

  float* corr  = (float*)d_out;
  float* covs  = corr + 67108864;   // B*T*64*64
  float* probs = corr + 83886080;   // + B*T*32*32

  float* ws   = (float*)d_ws;
  float* zws  = ws;                    // 1048576 floats
  int*   gate = (int*)(ws + 1048576);  // 2048 ints
  float* cinv = ws + 1050624;          // 1024
  float* htr  = ws + 1051648;          // 2048
  float* su   = ws + 1053696;          // 16777216

  hipLaunchKernelGGL(k_setup, dim3(1), dim3(256), 0, stream, Hw, logR, cinv, htr);
  hipLaunchKernelGGL(k_obs, dim3(4096), dim3(256), 0, stream, emb, w1, b1, w2, b2, ow, ob, probs, zws);
  hipLaunchKernelGGL(k_gate, dim3(8), dim3(256), 0, stream, probs, gate);
  hipLaunchKernelGGL(k_scan2, dim3(8), dim3(64), 0, stream, Fg, logQ, probs, gate, cinv, covs, su);
  hipLaunchKernelGGL(k_corr, dim3(16384), dim3(256), 0, stream, pos, zws, probs, gate, Hw, htr, su, corr);
}